// Round 1
// baseline (1579.152 us; speedup 1.0000x reference)
//
#include <hip/hip_runtime.h>
#include <cstdint>
#include <cstddef>

#define TK 10

__device__ __forceinline__ float4 ld4(const float* p){ return *(const float4*)p; }

// ---------------------------------------------------------------------------
// gemm64: C[M,N] = A[M,K] @ W[K,N] (+bias). Split-K over gridDim.z via atomicAdd
// (C must be pre-zeroed when gridDim.z > 1). Tile 64x64, BK=16, 4x4 microtile.
// ---------------------------------------------------------------------------
__global__ __launch_bounds__(256) void gemm64_kernel(const float* __restrict__ A,
    const float* __restrict__ W, const float* __restrict__ bias,
    float* __restrict__ C, int M, int N, int K)
{
  __shared__ float As[16][68];   // [k][m], pad 68 breaks write conflicts
  __shared__ float Bs[16][64];   // [k][n]
  const int t  = threadIdx.x;
  const int n0 = blockIdx.x * 64;
  const int m0 = blockIdx.y * 64;
  const int kchunk = K / gridDim.z;
  const int kbeg = blockIdx.z * kchunk;
  const int tm = t >> 4, tn = t & 15;
  const int ar = t >> 2, ak = (t & 3) << 2;
  const int bk = t >> 4, bc = (t & 15) << 2;
  const float* Ap = A + (size_t)(m0 + ar) * K + kbeg + ak;
  const float* Wp = W + (size_t)(kbeg + bk) * N + n0 + bc;
  float acc[4][4] = {};
  for (int kt = 0; kt < kchunk; kt += 16) {
    float4 a4 = ld4(Ap); Ap += 16;
    float4 b4 = ld4(Wp); Wp += (size_t)16 * N;
    __syncthreads();
    As[ak+0][ar] = a4.x; As[ak+1][ar] = a4.y; As[ak+2][ar] = a4.z; As[ak+3][ar] = a4.w;
    *(float4*)&Bs[bk][bc] = b4;
    __syncthreads();
    #pragma unroll
    for (int k = 0; k < 16; ++k) {
      float4 av = ld4(&As[k][tm << 2]);
      float4 bv = ld4(&Bs[k][tn << 2]);
      const float aa[4] = {av.x, av.y, av.z, av.w};
      const float bb[4] = {bv.x, bv.y, bv.z, bv.w};
      #pragma unroll
      for (int i = 0; i < 4; ++i)
        #pragma unroll
        for (int j = 0; j < 4; ++j)
          acc[i][j] = fmaf(aa[i], bb[j], acc[i][j]);
    }
  }
  const int cn = n0 + (tn << 2);
  if (gridDim.z == 1) {
    float bx = bias ? bias[cn+0] : 0.f;
    float by = bias ? bias[cn+1] : 0.f;
    float bz = bias ? bias[cn+2] : 0.f;
    float bw = bias ? bias[cn+3] : 0.f;
    #pragma unroll
    for (int i = 0; i < 4; ++i) {
      int m = m0 + (tm << 2) + i;
      float4 o = { acc[i][0]+bx, acc[i][1]+by, acc[i][2]+bz, acc[i][3]+bw };
      *(float4*)&C[(size_t)m * N + cn] = o;
    }
  } else {
    float badd[4] = {0.f, 0.f, 0.f, 0.f};
    if (bias && blockIdx.z == 0) {
      badd[0]=bias[cn]; badd[1]=bias[cn+1]; badd[2]=bias[cn+2]; badd[3]=bias[cn+3];
    }
    #pragma unroll
    for (int i = 0; i < 4; ++i) {
      int m = m0 + (tm << 2) + i;
      #pragma unroll
      for (int j = 0; j < 4; ++j)
        atomicAdd(&C[(size_t)m * N + cn + j], acc[i][j] + badd[j]);
    }
  }
}

// ---------------------------------------------------------------------------
// gemm128_bt: C[M,N] = A[M,K] @ Bq[N,K]^T  (Bq row-major [N,K], e.g. queue)
// Tile 128x128, BK=8, 8x8 microtile (2x2 of 4x4). Used for the score stripes.
// ---------------------------------------------------------------------------
__global__ __launch_bounds__(256) void gemm128_bt_kernel(const float* __restrict__ A,
    const float* __restrict__ Bq, float* __restrict__ C, int M, int N, int K)
{
  __shared__ float As[8][132];
  __shared__ float Bs[8][132];
  const int t  = threadIdx.x;
  const int n0 = blockIdx.x * 128;
  const int m0 = blockIdx.y * 128;
  const int tm = t >> 4, tn = t & 15;
  const int r  = t >> 1, kq = (t & 1) << 2;
  const float* Ap = A  + (size_t)(m0 + r) * K + kq;
  const float* Bp = Bq + (size_t)(n0 + r) * K + kq;
  float acc[2][2][4][4] = {};
  for (int k0 = 0; k0 < K; k0 += 8) {
    float4 a4 = ld4(Ap); Ap += 8;
    float4 b4 = ld4(Bp); Bp += 8;
    __syncthreads();
    As[kq+0][r]=a4.x; As[kq+1][r]=a4.y; As[kq+2][r]=a4.z; As[kq+3][r]=a4.w;
    Bs[kq+0][r]=b4.x; Bs[kq+1][r]=b4.y; Bs[kq+2][r]=b4.z; Bs[kq+3][r]=b4.w;
    __syncthreads();
    #pragma unroll
    for (int k = 0; k < 8; ++k) {
      float4 a0 = ld4(&As[k][tm << 2]);
      float4 a1 = ld4(&As[k][64 + (tm << 2)]);
      float4 b0 = ld4(&Bs[k][tn << 2]);
      float4 b1 = ld4(&Bs[k][64 + (tn << 2)]);
      const float am[2][4] = {{a0.x,a0.y,a0.z,a0.w},{a1.x,a1.y,a1.z,a1.w}};
      const float bb[2][4] = {{b0.x,b0.y,b0.z,b0.w},{b1.x,b1.y,b1.z,b1.w}};
      #pragma unroll
      for (int mi = 0; mi < 2; ++mi)
        #pragma unroll
        for (int nj = 0; nj < 2; ++nj)
          #pragma unroll
          for (int i = 0; i < 4; ++i)
            #pragma unroll
            for (int j = 0; j < 4; ++j)
              acc[mi][nj][i][j] = fmaf(am[mi][i], bb[nj][j], acc[mi][nj][i][j]);
    }
  }
  #pragma unroll
  for (int mi = 0; mi < 2; ++mi)
    #pragma unroll
    for (int i = 0; i < 4; ++i) {
      int m = m0 + mi*64 + (tm << 2) + i;
      #pragma unroll
      for (int nj = 0; nj < 2; ++nj) {
        int n = n0 + nj*64 + (tn << 2);
        float4 o = {acc[mi][nj][i][0], acc[mi][nj][i][1], acc[mi][nj][i][2], acc[mi][nj][i][3]};
        *(float4*)&C[(size_t)m * N + n] = o;
      }
    }
}

// ---------------------------------------------------------------------------
// BN column stats over 1024 rows -> scale/shift.  X: [heads][1024][N] via
// blockIdx.y. grid.x = N/64. gamma/beta indexed with stride gstride per head.
// ---------------------------------------------------------------------------
__global__ __launch_bounds__(256) void bn_stats_kernel(const float* __restrict__ X, int N,
    const float* __restrict__ gamma, const float* __restrict__ beta, int gstride,
    float* __restrict__ scale, float* __restrict__ shift)
{
  const int head = blockIdx.y;
  const float* Xh = X + (size_t)head * 1024 * N;
  const int lane = threadIdx.x & 63;
  const int col  = blockIdx.x * 64 + lane;
  const int rg   = threadIdx.x >> 6;
  float s = 0.f, ss = 0.f;
  const float* p = Xh + (size_t)(rg * 256) * N + col;
  for (int rr = 0; rr < 256; ++rr) { float v = *p; p += N; s += v; ss = fmaf(v, v, ss); }
  __shared__ float Ssum[4][64], Ssq[4][64];
  Ssum[rg][lane] = s; Ssq[rg][lane] = ss;
  __syncthreads();
  if (threadIdx.x < 64) {
    s  = Ssum[0][lane] + Ssum[1][lane] + Ssum[2][lane] + Ssum[3][lane];
    ss = Ssq[0][lane]  + Ssq[1][lane]  + Ssq[2][lane]  + Ssq[3][lane];
    float mean = s * (1.f / 1024.f);
    float var  = ss * (1.f / 1024.f) - mean * mean;
    float sc   = gamma[head * gstride + col] / sqrtf(var + 1e-5f);
    scale[head * N + col] = sc;
    shift[head * N + col] = beta[head * gstride + col] - mean * sc;
  }
}

// y = relu(x*scale[col] + shift[col]) in place, float4. total4 = elems/4.
__global__ void bn_apply_relu_kernel(float* __restrict__ X, int N,
    const float* __restrict__ scale, const float* __restrict__ shift, int total4)
{
  int i = blockIdx.x * 256 + threadIdx.x;
  if (i >= total4) return;
  size_t base = (size_t)i * 4;
  int col  = (int)(base % (size_t)N);
  int head = (int)(base / ((size_t)1024 * N));
  int sb = head * N + col;
  float4 v = *(float4*)&X[base];
  v.x = fmaxf(0.f, fmaf(v.x, scale[sb+0], shift[sb+0]));
  v.y = fmaxf(0.f, fmaf(v.y, scale[sb+1], shift[sb+1]));
  v.z = fmaxf(0.f, fmaf(v.z, scale[sb+2], shift[sb+2]));
  v.w = fmaxf(0.f, fmaf(v.w, scale[sb+3], shift[sb+3]));
  *(float4*)&X[base] = v;
}

// Build the 4 pre-BN fusion matrices from partial products P0..P2.
// H[i] = P_i + fus_w_row(1536+i) + fus_b (i<3); H[3] = P0+P1+P2 + sum rows + b.
__global__ void fuse_combine_kernel(const float* __restrict__ P,
    const float* __restrict__ fwr /* fus_w + 1536*512 */,
    const float* __restrict__ fb, float* __restrict__ H)
{
  int i = blockIdx.x * 256 + threadIdx.x;
  if (i >= 131072) return;           // 1024*512/4
  size_t base = (size_t)i * 4;
  int c = (int)(base & 511);
  float4 p0 = ld4(P + base), p1 = ld4(P + 524288 + base), p2 = ld4(P + 1048576 + base);
  float4 w0 = ld4(fwr + c), w1 = ld4(fwr + 512 + c), w2 = ld4(fwr + 1024 + c), b = ld4(fb + c);
  float4 h0, h1, h2, h3;
  h0.x=p0.x+w0.x+b.x; h0.y=p0.y+w0.y+b.y; h0.z=p0.z+w0.z+b.z; h0.w=p0.w+w0.w+b.w;
  h1.x=p1.x+w1.x+b.x; h1.y=p1.y+w1.y+b.y; h1.z=p1.z+w1.z+b.z; h1.w=p1.w+w1.w+b.w;
  h2.x=p2.x+w2.x+b.x; h2.y=p2.y+w2.y+b.y; h2.z=p2.z+w2.z+b.z; h2.w=p2.w+w2.w+b.w;
  h3.x=p0.x+p1.x+p2.x+w0.x+w1.x+w2.x+b.x;
  h3.y=p0.y+p1.y+p2.y+w0.y+w1.y+w2.y+b.y;
  h3.z=p0.z+p1.z+p2.z+w0.z+w1.z+w2.z+b.z;
  h3.w=p0.w+p1.w+p2.w+w0.w+w1.w+w2.w+b.w;
  *(float4*)&H[base]           = h0;
  *(float4*)&H[524288 + base]  = h1;
  *(float4*)&H[1048576 + base] = h2;
  *(float4*)&H[1572864 + base] = h3;
}

// gamma4/beta4 = {fus_sg[0..2], fus_g} / {fus_sb[0..2], fus_be}
__global__ void pack_gb_kernel(const float* __restrict__ sg, const float* __restrict__ sb,
    const float* __restrict__ g, const float* __restrict__ be,
    float* __restrict__ g4, float* __restrict__ b4)
{
  int i = blockIdx.x * 256 + threadIdx.x;
  if (i < 1536)      { g4[i] = sg[i];      b4[i] = sb[i]; }
  else if (i < 2048) { g4[i] = g[i-1536];  b4[i] = be[i-1536]; }
}

// out[row] = sum(X[row, 0:512]^2); one wave per row.
__global__ void row_sumsq_kernel(const float* __restrict__ X, float* __restrict__ out, int nrows)
{
  int row  = blockIdx.x * 4 + (threadIdx.x >> 6);
  int lane = threadIdx.x & 63;
  if (row >= nrows) return;
  const float* p = X + (size_t)row * 512 + lane * 8;
  float4 a = ld4(p), b = ld4(p + 4);
  float s = a.x*a.x + a.y*a.y + a.z*a.z + a.w*a.w
          + b.x*b.x + b.y*b.y + b.z*b.z + b.w*b.w;
  for (int off = 32; off; off >>= 1) s += __shfl_down(s, off, 64);
  if (lane == 0) out[row] = s;
}

// ---------------------------------------------------------------------------
// topk_scan: per stripe row, d2 = qn + kn[q] - 2*S[row,q]; keep global top-10
// smallest (d2, idx) lexicographic (matches lax.top_k stable tie-break).
// One block (256 thr) per row: per-thread sorted top-10, then 10 argmin rounds.
// ---------------------------------------------------------------------------
__global__ __launch_bounds__(256) void topk_scan_kernel(const float* __restrict__ S,
    const float* __restrict__ qn, const float* __restrict__ kn, int rowbase,
    float* __restrict__ topd2, int* __restrict__ topidx)
{
  const int row  = blockIdx.x;
  const int grow = rowbase + row;
  const float* Srow = S + (size_t)row * 32768;
  const float qnr = qn[grow];
  const int t = threadIdx.x;
  float vals[TK]; int idxs[TK];
  #pragma unroll
  for (int j = 0; j < TK; ++j) { vals[j] = __builtin_inff(); idxs[j] = 0x7fffffff; }
  for (int q = t; q < 32768; q += 256) {
    float d2 = (qnr + kn[q]) - 2.f * Srow[q];
    if (d2 < vals[TK-1]) {
      float cv = d2; int ci = q;
      #pragma unroll
      for (int j = 0; j < TK; ++j) {
        bool less = (cv < vals[j]) || (cv == vals[j] && ci < idxs[j]);
        float tv = less ? vals[j] : cv; int ti = less ? idxs[j] : ci;
        vals[j] = less ? cv : vals[j]; idxs[j] = less ? ci : idxs[j];
        cv = tv; ci = ti;
      }
    }
  }
  __shared__ float Lv[256 * TK];
  __shared__ int   Li[256 * TK];
  __shared__ float Wv[4]; __shared__ int Wi[4]; __shared__ int Wslot[4];
  #pragma unroll
  for (int j = 0; j < TK; ++j) { Lv[t*TK + j] = vals[j]; Li[t*TK + j] = idxs[j]; }
  __syncthreads();
  const int lane = t & 63, wid = t >> 6;
  for (int sel = 0; sel < TK; ++sel) {
    float bv = __builtin_inff(); int bi = 0x7fffffff; int bs = -1;
    #pragma unroll
    for (int j = 0; j < TK; ++j) {
      float v = Lv[t*TK + j]; int id = Li[t*TK + j];
      if (v < bv || (v == bv && id < bi)) { bv = v; bi = id; bs = t*TK + j; }
    }
    for (int off = 32; off; off >>= 1) {
      float ov = __shfl_down(bv, off, 64);
      int   oi = __shfl_down(bi, off, 64);
      int   os = __shfl_down(bs, off, 64);
      if (ov < bv || (ov == bv && oi < bi)) { bv = ov; bi = oi; bs = os; }
    }
    if (lane == 0) { Wv[wid] = bv; Wi[wid] = bi; Wslot[wid] = bs; }
    __syncthreads();
    if (t == 0) {
      bv = Wv[0]; bi = Wi[0]; bs = Wslot[0];
      for (int w2 = 1; w2 < 4; ++w2)
        if (Wv[w2] < bv || (Wv[w2] == bv && Wi[w2] < bi)) { bv = Wv[w2]; bi = Wi[w2]; bs = Wslot[w2]; }
      topd2[grow*TK + sel] = bv;
      topidx[grow*TK + sel] = bi;
      Lv[bs] = __builtin_inff(); Li[bs] = 0x7fffffff;
    }
    __syncthreads();
  }
}

// weights = softmax(-sqrt(max(d2,0))/TEMP); neigh = sum_k w_k * queue[idx_k].
__global__ void knn_gather_kernel(const float* __restrict__ topd2, const int* __restrict__ topidx,
    const float* __restrict__ queue, float* __restrict__ neigh)
{
  const int row = blockIdx.x;
  const int t = threadIdx.x;   // 64
  __shared__ float ls[TK]; __shared__ float wv[TK]; __shared__ int wid[TK];
  if (t < TK) {
    float d = sqrtf(fmaxf(topd2[row*TK + t], 0.f));
    ls[t]  = -d / 0.07f;
    wid[t] = topidx[row*TK + t];
  }
  __syncthreads();
  if (t < TK) {
    float m = ls[0];
    #pragma unroll
    for (int j = 1; j < TK; ++j) m = fmaxf(m, ls[j]);
    wv[t] = __expf(ls[t] - m);
  }
  __syncthreads();
  float ssum = 0.f;
  #pragma unroll
  for (int j = 0; j < TK; ++j) ssum += wv[j];
  float inv = 1.f / ssum;
  #pragma unroll
  for (int u = 0; u < 8; ++u) {
    int c = u * 64 + t;
    float acc = 0.f;
    #pragma unroll
    for (int k = 0; k < TK; ++k)
      acc = fmaf(wv[k] * inv, queue[(size_t)wid[k] * 512 + c], acc);
    neigh[(size_t)row * 512 + c] = acc;
  }
}

// out[r,c] = bias[c] + sum_k Z[r,k]*W2[k,c]  (N=18 classifier head)
__global__ void gemm_n18_kernel(const float* __restrict__ Z, const float* __restrict__ W2,
    const float* __restrict__ b2, float* __restrict__ out, int Mrows)
{
  int o = blockIdx.x * 256 + threadIdx.x;
  if (o >= Mrows * 18) return;
  int r = o / 18, c = o - r * 18;
  const float* zp = Z + (size_t)r * 512;
  float acc = b2[c];
  #pragma unroll 8
  for (int k = 0; k < 512; ++k) acc = fmaf(zp[k], W2[k*18 + c], acc);
  out[o] = acc;
}

// ---------------------------------------------------------------------------
extern "C" void kernel_launch(void* const* d_in, const int* in_sizes, int n_in,
                              void* d_out, int out_size, void* d_ws, size_t ws_size,
                              hipStream_t stream)
{
  #define IN(i) ((const float*)d_in[i])
  const float* img_feat = IN(0);
  const float* option   = IN(1);
  const float* semantic = IN(2);
  const float* queue    = IN(3);
  const float* vae_w1 = IN(4);  const float* vae_b1 = IN(5);
  const float* vae_g1 = IN(6);  const float* vae_be1 = IN(7);
  const float* vae_w2 = IN(8);  const float* vae_b2 = IN(9);
  const float* opt_w1 = IN(10); const float* opt_b1 = IN(11);
  const float* opt_g1 = IN(12); const float* opt_be1 = IN(13);
  const float* opt_w2 = IN(14); const float* opt_b2 = IN(15);
  const float* opt_g2 = IN(16); const float* opt_be2 = IN(17);
  const float* sem_w1 = IN(18); const float* sem_b1 = IN(19);
  const float* sem_g1 = IN(20); const float* sem_be1 = IN(21);
  const float* sem_w2 = IN(22); const float* sem_b2 = IN(23);
  const float* sem_g2 = IN(24); const float* sem_be2 = IN(25);
  const float* fus_w = IN(26);  const float* fus_b = IN(27);
  const float* fus_g = IN(28);  const float* fus_be = IN(29);
  const float* fus_sg = IN(30); const float* fus_sb = IN(31);
  const float* cls_w1 = IN(32); const float* cls_b1 = IN(33);
  const float* cls_g = IN(34);  const float* cls_be = IN(35);
  const float* cls_w2 = IN(36); const float* cls_b2 = IN(37);

  float* ws = (float*)d_ws;
  size_t off = 0;
  auto alloc = [&](size_t n) { float* p = ws + off; off += (n + 255) & ~(size_t)255; return p; };

  // stripe rows: 256 if workspace allows (~71 MB), else 128 (~55 MB)
  const int srows = (ws_size >= (size_t)74 * 1024 * 1024) ? 256 : 128;

  float* S    = alloc((size_t)srows * 32768);
  float* H    = alloc(4 * 1024 * 512);
  float* Z4   = alloc(4 * 1024 * 512);
  float* zstart = ws + off;          // ---- region zeroed for split-K atomics ----
  float* t1   = alloc(1024 * 512);
  float* img  = alloc(1024 * 512);
  float* o1   = alloc(1024 * 192);
  float* optb = alloc(1024 * 512);
  float* s1   = alloc(1024 * 192);
  float* semb = alloc(1024 * 512);
  float* P    = alloc(3 * 1024 * 512);
  float* Z1   = alloc(1024 * 512);
  size_t zbytes = (size_t)((ws + off) - zstart) * 4;   // ---- end zero region ----
  float* neigh = alloc(1024 * 512);
  float* qn   = alloc(1024);
  float* kn   = alloc(32768);
  float* scv  = alloc(512);  float* shv  = alloc(512);
  float* sco1 = alloc(192);  float* sho1 = alloc(192);
  float* sco2 = alloc(512);  float* sho2 = alloc(512);
  float* scs1 = alloc(192);  float* shs1 = alloc(192);
  float* scs2 = alloc(512);  float* shs2 = alloc(512);
  float* scf  = alloc(4*512); float* shf = alloc(4*512);
  float* scc4 = alloc(4*512); float* shc4 = alloc(4*512);
  float* scc1 = alloc(512);  float* shc1 = alloc(512);
  float* g4   = alloc(4*512); float* b4  = alloc(4*512);
  float* topd2 = alloc(1024 * TK);
  int*   topidx = (int*)alloc(1024 * TK);

  hipMemsetAsync(zstart, 0, zbytes, stream);

  dim3 blk(256);
  // --- VAE branch: img = relu(bn(img_feat@W1+b1)) @ W2 + b2
  gemm64_kernel<<<dim3(8,16,4), blk, 0, stream>>>(img_feat, vae_w1, vae_b1, t1, 1024, 512, 2048);
  bn_stats_kernel<<<dim3(8,1), blk, 0, stream>>>(t1, 512, vae_g1, vae_be1, 0, scv, shv);
  bn_apply_relu_kernel<<<dim3(512), blk, 0, stream>>>(t1, 512, scv, shv, 131072);
  gemm64_kernel<<<dim3(8,16,4), blk, 0, stream>>>(t1, vae_w2, vae_b2, img, 1024, 512, 512);
  // --- option encoder
  gemm64_kernel<<<dim3(3,16,8), blk, 0, stream>>>(option, opt_w1, opt_b1, o1, 1024, 192, 768);
  bn_stats_kernel<<<dim3(3,1), blk, 0, stream>>>(o1, 192, opt_g1, opt_be1, 0, sco1, sho1);
  bn_apply_relu_kernel<<<dim3(192), blk, 0, stream>>>(o1, 192, sco1, sho1, 49152);
  gemm64_kernel<<<dim3(8,16,2), blk, 0, stream>>>(o1, opt_w2, opt_b2, optb, 1024, 512, 192);
  bn_stats_kernel<<<dim3(8,1), blk, 0, stream>>>(optb, 512, opt_g2, opt_be2, 0, sco2, sho2);
  bn_apply_relu_kernel<<<dim3(512), blk, 0, stream>>>(optb, 512, sco2, sho2, 131072);
  // --- semantic encoder
  gemm64_kernel<<<dim3(3,16,8), blk, 0, stream>>>(semantic, sem_w1, sem_b1, s1, 1024, 192, 768);
  bn_stats_kernel<<<dim3(3,1), blk, 0, stream>>>(s1, 192, sem_g1, sem_be1, 0, scs1, shs1);
  bn_apply_relu_kernel<<<dim3(192), blk, 0, stream>>>(s1, 192, scs1, shs1, 49152);
  gemm64_kernel<<<dim3(8,16,2), blk, 0, stream>>>(s1, sem_w2, sem_b2, semb, 1024, 512, 192);
  bn_stats_kernel<<<dim3(8,1), blk, 0, stream>>>(semb, 512, sem_g2, sem_be2, 0, scs2, shs2);
  bn_apply_relu_kernel<<<dim3(512), blk, 0, stream>>>(semb, 512, scs2, shs2, 131072);
  // --- fusion partial products P_i = feat_i @ fus_w[i*512:(i+1)*512]
  gemm64_kernel<<<dim3(8,16,4), blk, 0, stream>>>(img,  fus_w,            nullptr, P,           1024, 512, 512);
  gemm64_kernel<<<dim3(8,16,4), blk, 0, stream>>>(optb, fus_w + 262144,   nullptr, P + 524288,  1024, 512, 512);
  gemm64_kernel<<<dim3(8,16,4), blk, 0, stream>>>(semb, fus_w + 524288,   nullptr, P + 1048576, 1024, 512, 512);
  fuse_combine_kernel<<<dim3(512), blk, 0, stream>>>(P, fus_w + 1536*512, fus_b, H);
  pack_gb_kernel<<<dim3(8), blk, 0, stream>>>(fus_sg, fus_sb, fus_g, fus_be, g4, b4);
  bn_stats_kernel<<<dim3(8,4), blk, 0, stream>>>(H, 512, g4, b4, 512, scf, shf);
  bn_apply_relu_kernel<<<dim3(2048), blk, 0, stream>>>(H, 512, scf, shf, 524288);
  // --- classifier on heads 0..3 (out_0..2, fused), batched as M=4096
  gemm64_kernel<<<dim3(8,64,1), blk, 0, stream>>>(H, cls_w1, cls_b1, Z4, 4096, 512, 512);
  bn_stats_kernel<<<dim3(8,4), blk, 0, stream>>>(Z4, 512, cls_g, cls_be, 0, scc4, shc4);
  bn_apply_relu_kernel<<<dim3(2048), blk, 0, stream>>>(Z4, 512, scc4, shc4, 524288);
  gemm_n18_kernel<<<dim3((4096*18 + 255)/256), blk, 0, stream>>>(Z4, cls_w2, cls_b2, (float*)d_out, 4096);
  // --- kNN retrieval over queue
  const float* fused = H + (size_t)3 * 1024 * 512;
  row_sumsq_kernel<<<dim3(256), blk, 0, stream>>>(fused, qn, 1024);
  row_sumsq_kernel<<<dim3(8192), blk, 0, stream>>>(queue, kn, 32768);
  for (int sbase = 0; sbase < 1024; sbase += srows) {
    gemm128_bt_kernel<<<dim3(256, srows/128), blk, 0, stream>>>(fused + (size_t)sbase*512, queue, S, srows, 32768, 512);
    topk_scan_kernel<<<dim3(srows), blk, 0, stream>>>(S, qn, kn, sbase, topd2, topidx);
  }
  knn_gather_kernel<<<dim3(1024), dim3(64), 0, stream>>>(topd2, topidx, queue, neigh);
  // --- classifier on neigh (head 4)
  gemm64_kernel<<<dim3(8,16,4), blk, 0, stream>>>(neigh, cls_w1, cls_b1, Z1, 1024, 512, 512);
  bn_stats_kernel<<<dim3(8,1), blk, 0, stream>>>(Z1, 512, cls_g, cls_be, 0, scc1, shc1);
  bn_apply_relu_kernel<<<dim3(512), blk, 0, stream>>>(Z1, 512, scc1, shc1, 131072);
  gemm_n18_kernel<<<dim3((1024*18 + 255)/256), blk, 0, stream>>>(Z1, cls_w2, cls_b2, (float*)d_out + 4*1024*18, 1024);
  #undef IN
}

// Round 2
// 1407.249 us; speedup vs baseline: 1.1222x; 1.1222x over previous
//
#include <hip/hip_runtime.h>
#include <cstdint>
#include <cstddef>

#define TK 10

typedef unsigned short u16;
typedef __attribute__((ext_vector_type(8))) short short8;
typedef __attribute__((ext_vector_type(4))) float f32x4;

__device__ __forceinline__ float4 ld4(const float* p){ return *(const float4*)p; }

// fp32 -> bf16 round-to-nearest-even
__device__ __forceinline__ u16 bfr(float x){
  unsigned u = __float_as_uint(x);
  return (u16)((u + 0x7FFFu + ((u >> 16) & 1u)) >> 16);
}

// ---------------------------------------------------------------------------
// gemm64: C[M,N] = A[M,K] @ W[K,N] (+bias). Split-K over gridDim.z via atomicAdd
// (C must be pre-zeroed when gridDim.z > 1). Tile 64x64, BK=16, 4x4 microtile.
// ---------------------------------------------------------------------------
__global__ __launch_bounds__(256) void gemm64_kernel(const float* __restrict__ A,
    const float* __restrict__ W, const float* __restrict__ bias,
    float* __restrict__ C, int M, int N, int K)
{
  __shared__ float As[16][68];
  __shared__ float Bs[16][64];
  const int t  = threadIdx.x;
  const int n0 = blockIdx.x * 64;
  const int m0 = blockIdx.y * 64;
  const int kchunk = K / gridDim.z;
  const int kbeg = blockIdx.z * kchunk;
  const int tm = t >> 4, tn = t & 15;
  const int ar = t >> 2, ak = (t & 3) << 2;
  const int bk = t >> 4, bc = (t & 15) << 2;
  const float* Ap = A + (size_t)(m0 + ar) * K + kbeg + ak;
  const float* Wp = W + (size_t)(kbeg + bk) * N + n0 + bc;
  float acc[4][4] = {};
  for (int kt = 0; kt < kchunk; kt += 16) {
    float4 a4 = ld4(Ap); Ap += 16;
    float4 b4 = ld4(Wp); Wp += (size_t)16 * N;
    __syncthreads();
    As[ak+0][ar] = a4.x; As[ak+1][ar] = a4.y; As[ak+2][ar] = a4.z; As[ak+3][ar] = a4.w;
    *(float4*)&Bs[bk][bc] = b4;
    __syncthreads();
    #pragma unroll
    for (int k = 0; k < 16; ++k) {
      float4 av = ld4(&As[k][tm << 2]);
      float4 bv = ld4(&Bs[k][tn << 2]);
      const float aa[4] = {av.x, av.y, av.z, av.w};
      const float bb[4] = {bv.x, bv.y, bv.z, bv.w};
      #pragma unroll
      for (int i = 0; i < 4; ++i)
        #pragma unroll
        for (int j = 0; j < 4; ++j)
          acc[i][j] = fmaf(aa[i], bb[j], acc[i][j]);
    }
  }
  const int cn = n0 + (tn << 2);
  if (gridDim.z == 1) {
    float bx = bias ? bias[cn+0] : 0.f;
    float by = bias ? bias[cn+1] : 0.f;
    float bz = bias ? bias[cn+2] : 0.f;
    float bw = bias ? bias[cn+3] : 0.f;
    #pragma unroll
    for (int i = 0; i < 4; ++i) {
      int m = m0 + (tm << 2) + i;
      float4 o = { acc[i][0]+bx, acc[i][1]+by, acc[i][2]+bz, acc[i][3]+bw };
      *(float4*)&C[(size_t)m * N + cn] = o;
    }
  } else {
    float badd[4] = {0.f, 0.f, 0.f, 0.f};
    if (bias && blockIdx.z == 0) {
      badd[0]=bias[cn]; badd[1]=bias[cn+1]; badd[2]=bias[cn+2]; badd[3]=bias[cn+3];
    }
    #pragma unroll
    for (int i = 0; i < 4; ++i) {
      int m = m0 + (tm << 2) + i;
      #pragma unroll
      for (int j = 0; j < 4; ++j)
        atomicAdd(&C[(size_t)m * N + cn + j], acc[i][j] + badd[j]);
    }
  }
}

// ---------------------------------------------------------------------------
// score_mfma: C[Mt,32768] = A[Mt,512] @ queue[32768,512]^T in bf16 MFMA,
// fp32 accumulate. In-register fp32->bf16 cvt during LDS staging.
// Block 256 thr = 4 waves (2x2), tile 128x128, BK=64, 16x16x32 MFMA.
// LDS XOR swizzle on 16B chunks: phys_chunk = row*8 + (c ^ (row&7)).
// ---------------------------------------------------------------------------
__global__ __launch_bounds__(256) void score_mfma_kernel(
    const float* __restrict__ A, const float* __restrict__ Bq,
    float* __restrict__ C)
{
  __shared__ u16 At[128 * 64];
  __shared__ u16 Bt[128 * 64];
  const int t  = threadIdx.x;
  const int n0 = blockIdx.x * 128;
  const int m0 = blockIdx.y * 128;

  // staging: 1024 chunks of 8 elems per tile; 4 chunks per thread per operand
  u16* ldsA[4]; u16* ldsB[4];
  const float* gA[4]; const float* gB[4];
  #pragma unroll
  for (int i = 0; i < 4; ++i) {
    int L = i * 256 + t;
    int row = L >> 3, c = L & 7;
    int phys = row * 8 + (c ^ (row & 7));
    ldsA[i] = &At[phys * 8]; ldsB[i] = &Bt[phys * 8];
    gA[i] = A  + (size_t)(m0 + row) * 512 + c * 8;
    gB[i] = Bq + (size_t)(n0 + row) * 512 + c * 8;
  }

  const int lane = t & 63, w = t >> 6;
  const int wm = (w >> 1) * 64, wn = (w & 1) * 64;
  const int q = lane >> 4, rl = lane & 15;

  f32x4 acc[4][4];
  const f32x4 z4 = {0.f, 0.f, 0.f, 0.f};
  #pragma unroll
  for (int i = 0; i < 4; ++i)
    #pragma unroll
    for (int j = 0; j < 4; ++j) acc[i][j] = z4;

  union U16x8 { u16 u[8]; float4 f4; };

  for (int k0 = 0; k0 < 512; k0 += 64) {
    float4 ra[4][2], rb[4][2];
    #pragma unroll
    for (int i = 0; i < 4; ++i) {
      ra[i][0] = ld4(gA[i]); ra[i][1] = ld4(gA[i] + 4);
      rb[i][0] = ld4(gB[i]); rb[i][1] = ld4(gB[i] + 4);
      gA[i] += 64; gB[i] += 64;
    }
    __syncthreads();
    #pragma unroll
    for (int i = 0; i < 4; ++i) {
      U16x8 pa, pb;
      pa.u[0]=bfr(ra[i][0].x); pa.u[1]=bfr(ra[i][0].y); pa.u[2]=bfr(ra[i][0].z); pa.u[3]=bfr(ra[i][0].w);
      pa.u[4]=bfr(ra[i][1].x); pa.u[5]=bfr(ra[i][1].y); pa.u[6]=bfr(ra[i][1].z); pa.u[7]=bfr(ra[i][1].w);
      pb.u[0]=bfr(rb[i][0].x); pb.u[1]=bfr(rb[i][0].y); pb.u[2]=bfr(rb[i][0].z); pb.u[3]=bfr(rb[i][0].w);
      pb.u[4]=bfr(rb[i][1].x); pb.u[5]=bfr(rb[i][1].y); pb.u[6]=bfr(rb[i][1].z); pb.u[7]=bfr(rb[i][1].w);
      *(float4*)ldsA[i] = pa.f4;
      *(float4*)ldsB[i] = pb.f4;
    }
    __syncthreads();
    #pragma unroll
    for (int kk = 0; kk < 2; ++kk) {
      short8 af[4], bfv[4];
      #pragma unroll
      for (int mt = 0; mt < 4; ++mt) {
        int r = wm + mt * 16 + rl;
        int cc = (kk * 4 + q) ^ (r & 7);
        af[mt] = *(const short8*)&At[(r * 8 + cc) * 8];
      }
      #pragma unroll
      for (int nt = 0; nt < 4; ++nt) {
        int r = wn + nt * 16 + rl;
        int cc = (kk * 4 + q) ^ (r & 7);
        bfv[nt] = *(const short8*)&Bt[(r * 8 + cc) * 8];
      }
      #pragma unroll
      for (int mt = 0; mt < 4; ++mt)
        #pragma unroll
        for (int nt = 0; nt < 4; ++nt)
          acc[mt][nt] = __builtin_amdgcn_mfma_f32_16x16x32_bf16(af[mt], bfv[nt], acc[mt][nt], 0, 0, 0);
    }
  }
  // epilogue: C/D layout col = lane&15, row = q*4 + reg  [m89-verified]
  #pragma unroll
  for (int mt = 0; mt < 4; ++mt)
    #pragma unroll
    for (int nt = 0; nt < 4; ++nt) {
      int m = m0 + wm + mt * 16 + q * 4;
      int n = n0 + wn + nt * 16 + rl;
      #pragma unroll
      for (int reg = 0; reg < 4; ++reg)
        C[(size_t)(m + reg) * 32768 + n] = acc[mt][nt][reg];
    }
}

// ---------------------------------------------------------------------------
// BN column stats over 1024 rows -> scale/shift.
// ---------------------------------------------------------------------------
__global__ __launch_bounds__(256) void bn_stats_kernel(const float* __restrict__ X, int N,
    const float* __restrict__ gamma, const float* __restrict__ beta, int gstride,
    float* __restrict__ scale, float* __restrict__ shift)
{
  const int head = blockIdx.y;
  const float* Xh = X + (size_t)head * 1024 * N;
  const int lane = threadIdx.x & 63;
  const int col  = blockIdx.x * 64 + lane;
  const int rg   = threadIdx.x >> 6;
  float s = 0.f, ss = 0.f;
  const float* p = Xh + (size_t)(rg * 256) * N + col;
  for (int rr = 0; rr < 256; ++rr) { float v = *p; p += N; s += v; ss = fmaf(v, v, ss); }
  __shared__ float Ssum[4][64], Ssq[4][64];
  Ssum[rg][lane] = s; Ssq[rg][lane] = ss;
  __syncthreads();
  if (threadIdx.x < 64) {
    s  = Ssum[0][lane] + Ssum[1][lane] + Ssum[2][lane] + Ssum[3][lane];
    ss = Ssq[0][lane]  + Ssq[1][lane]  + Ssq[2][lane]  + Ssq[3][lane];
    float mean = s * (1.f / 1024.f);
    float var  = ss * (1.f / 1024.f) - mean * mean;
    float sc   = gamma[head * gstride + col] / sqrtf(var + 1e-5f);
    scale[head * N + col] = sc;
    shift[head * N + col] = beta[head * gstride + col] - mean * sc;
  }
}

__global__ void bn_apply_relu_kernel(float* __restrict__ X, int N,
    const float* __restrict__ scale, const float* __restrict__ shift, int total4)
{
  int i = blockIdx.x * 256 + threadIdx.x;
  if (i >= total4) return;
  size_t base = (size_t)i * 4;
  int col  = (int)(base % (size_t)N);
  int head = (int)(base / ((size_t)1024 * N));
  int sb = head * N + col;
  float4 v = *(float4*)&X[base];
  v.x = fmaxf(0.f, fmaf(v.x, scale[sb+0], shift[sb+0]));
  v.y = fmaxf(0.f, fmaf(v.y, scale[sb+1], shift[sb+1]));
  v.z = fmaxf(0.f, fmaf(v.z, scale[sb+2], shift[sb+2]));
  v.w = fmaxf(0.f, fmaf(v.w, scale[sb+3], shift[sb+3]));
  *(float4*)&X[base] = v;
}

__global__ void fuse_combine_kernel(const float* __restrict__ P,
    const float* __restrict__ fwr, const float* __restrict__ fb, float* __restrict__ H)
{
  int i = blockIdx.x * 256 + threadIdx.x;
  if (i >= 131072) return;
  size_t base = (size_t)i * 4;
  int c = (int)(base & 511);
  float4 p0 = ld4(P + base), p1 = ld4(P + 524288 + base), p2 = ld4(P + 1048576 + base);
  float4 w0 = ld4(fwr + c), w1 = ld4(fwr + 512 + c), w2 = ld4(fwr + 1024 + c), b = ld4(fb + c);
  float4 h0, h1, h2, h3;
  h0.x=p0.x+w0.x+b.x; h0.y=p0.y+w0.y+b.y; h0.z=p0.z+w0.z+b.z; h0.w=p0.w+w0.w+b.w;
  h1.x=p1.x+w1.x+b.x; h1.y=p1.y+w1.y+b.y; h1.z=p1.z+w1.z+b.z; h1.w=p1.w+w1.w+b.w;
  h2.x=p2.x+w2.x+b.x; h2.y=p2.y+w2.y+b.y; h2.z=p2.z+w2.z+b.z; h2.w=p2.w+w2.w+b.w;
  h3.x=p0.x+p1.x+p2.x+w0.x+w1.x+w2.x+b.x;
  h3.y=p0.y+p1.y+p2.y+w0.y+w1.y+w2.y+b.y;
  h3.z=p0.z+p1.z+p2.z+w0.z+w1.z+w2.z+b.z;
  h3.w=p0.w+p1.w+p2.w+w0.w+w1.w+w2.w+b.w;
  *(float4*)&H[base]           = h0;
  *(float4*)&H[524288 + base]  = h1;
  *(float4*)&H[1048576 + base] = h2;
  *(float4*)&H[1572864 + base] = h3;
}

__global__ void pack_gb_kernel(const float* __restrict__ sg, const float* __restrict__ sb,
    const float* __restrict__ g, const float* __restrict__ be,
    float* __restrict__ g4, float* __restrict__ b4)
{
  int i = blockIdx.x * 256 + threadIdx.x;
  if (i < 1536)      { g4[i] = sg[i];      b4[i] = sb[i]; }
  else if (i < 2048) { g4[i] = g[i-1536];  b4[i] = be[i-1536]; }
}

__global__ void row_sumsq_kernel(const float* __restrict__ X, float* __restrict__ out, int nrows)
{
  int row  = blockIdx.x * 4 + (threadIdx.x >> 6);
  int lane = threadIdx.x & 63;
  if (row >= nrows) return;
  const float* p = X + (size_t)row * 512 + lane * 8;
  float4 a = ld4(p), b = ld4(p + 4);
  float s = a.x*a.x + a.y*a.y + a.z*a.z + a.w*a.w
          + b.x*b.x + b.y*b.y + b.z*b.z + b.w*b.w;
  for (int off = 32; off; off >>= 1) s += __shfl_down(s, off, 64);
  if (lane == 0) out[row] = s;
}

// ---------------------------------------------------------------------------
// topk_rescue: approx d2 from bf16 scores -> per-thread top-8 -> global top-32
// candidate set -> exact fp32 d2 for candidates -> exact lexicographic top-10.
// One block (256 thr) per stripe row.
// ---------------------------------------------------------------------------
__global__ __launch_bounds__(256) void topk_rescue_kernel(const float* __restrict__ S,
    const float* __restrict__ fusedF, const float* __restrict__ queue,
    const float* __restrict__ qn, const float* __restrict__ kn, int rowbase,
    float* __restrict__ topd2, int* __restrict__ topidx)
{
  const int row  = blockIdx.x;
  const int grow = rowbase + row;
  const float* Srow = S + (size_t)row * 32768;
  const float qnr = qn[grow];
  const int t = threadIdx.x;
  const float INF = __builtin_inff();

  // phase 1: per-thread sorted top-8 over this thread's 128 columns (approx d2)
  float vals[8]; int idxs[8];
  #pragma unroll
  for (int j = 0; j < 8; ++j) { vals[j] = INF; idxs[j] = 0x7fffffff; }
  for (int q = t; q < 32768; q += 256) {
    float d2 = (qnr + kn[q]) - 2.f * Srow[q];
    if (d2 < vals[7]) {
      float cv = d2; int ci = q;
      #pragma unroll
      for (int j = 0; j < 8; ++j) {
        bool less = (cv < vals[j]) || (cv == vals[j] && ci < idxs[j]);
        float tv = less ? vals[j] : cv; int ti = less ? idxs[j] : ci;
        vals[j] = less ? cv : vals[j]; idxs[j] = less ? ci : idxs[j];
        cv = tv; ci = ti;
      }
    }
  }

  __shared__ float Lv[2048]; __shared__ int Li[2048];
  __shared__ float Wv[4];    __shared__ int Wi[4];
  __shared__ int   Ci[32];   __shared__ float Cd[32];
  __shared__ int   bcastI;
  __shared__ float fr[512];
  #pragma unroll
  for (int j = 0; j < 8; ++j) { Lv[t*8 + j] = vals[j]; Li[t*8 + j] = idxs[j]; }
  fr[t] = fusedF[(size_t)grow * 512 + t];
  fr[t + 256] = fusedF[(size_t)grow * 512 + t + 256];
  __syncthreads();

  // phase 2: extract global top-32 candidate indices
  const int lane = t & 63, wid = t >> 6;
  for (int sel = 0; sel < 32; ++sel) {
    float bv = INF; int bi = 0x7fffffff;
    #pragma unroll
    for (int j = 0; j < 8; ++j) {
      float v = Lv[t*8 + j]; int id = Li[t*8 + j];
      if (v < bv || (v == bv && id < bi)) { bv = v; bi = id; }
    }
    #pragma unroll
    for (int off = 32; off >= 1; off >>= 1) {
      float ov = __shfl_down(bv, off, 64);
      int   oi = __shfl_down(bi, off, 64);
      if (ov < bv || (ov == bv && oi < bi)) { bv = ov; bi = oi; }
    }
    if (lane == 0) { Wv[wid] = bv; Wi[wid] = bi; }
    __syncthreads();
    if (t == 0) {
      bv = Wv[0]; bi = Wi[0];
      for (int w2 = 1; w2 < 4; ++w2)
        if (Wv[w2] < bv || (Wv[w2] == bv && Wi[w2] < bi)) { bv = Wv[w2]; bi = Wi[w2]; }
      Ci[sel] = bi; bcastI = bi;
    }
    __syncthreads();
    int kill = bcastI;
    #pragma unroll
    for (int j = 0; j < 8; ++j)
      if (Li[t*8 + j] == kill) { Lv[t*8 + j] = INF; Li[t*8 + j] = 0x7fffffff; }
  }
  __syncthreads();

  // phase 3: exact fp32 d2 for the 32 candidates (8 threads per candidate)
  {
    int c = t >> 3, s = t & 7;
    int qi = Ci[c];
    const float* qp = queue + (size_t)qi * 512 + s * 64;
    const float* fp = fr + s * 64;
    float dot = 0.f;
    #pragma unroll
    for (int j = 0; j < 16; ++j) {
      float4 a = ld4(fp + j*4); float4 b = ld4(qp + j*4);
      dot += a.x*b.x + a.y*b.y + a.z*b.z + a.w*b.w;
    }
    dot += __shfl_down(dot, 4, 8);
    dot += __shfl_down(dot, 2, 8);
    dot += __shfl_down(dot, 1, 8);
    if (s == 0) Cd[c] = qnr + kn[qi] - 2.f * dot;
  }
  __syncthreads();

  // phase 4: exact lexicographic top-10 of the 32 candidates (wave 0)
  if (t < 64) {
    float v = (t < 32) ? Cd[t] : INF;
    int  id = (t < 32) ? Ci[t] : 0x7fffffff;
    for (int sel = 0; sel < TK; ++sel) {
      float bv = v; int bi = id;
      #pragma unroll
      for (int off = 32; off >= 1; off >>= 1) {
        float ov = __shfl_down(bv, off, 64);
        int   oi = __shfl_down(bi, off, 64);
        if (ov < bv || (ov == bv && oi < bi)) { bv = ov; bi = oi; }
      }
      bv = __shfl(bv, 0, 64); bi = __shfl(bi, 0, 64);
      if (t == 0) { topd2[grow*TK + sel] = bv; topidx[grow*TK + sel] = bi; }
      if (id == bi) { v = INF; id = 0x7fffffff; }
    }
  }
}

__global__ void knn_gather_kernel(const float* __restrict__ topd2, const int* __restrict__ topidx,
    const float* __restrict__ queue, float* __restrict__ neigh)
{
  const int row = blockIdx.x;
  const int t = threadIdx.x;   // 64
  __shared__ float ls[TK]; __shared__ float wv[TK]; __shared__ int wid[TK];
  if (t < TK) {
    float d = sqrtf(fmaxf(topd2[row*TK + t], 0.f));
    ls[t]  = -d / 0.07f;
    wid[t] = topidx[row*TK + t];
  }
  __syncthreads();
  if (t < TK) {
    float m = ls[0];
    #pragma unroll
    for (int j = 1; j < TK; ++j) m = fmaxf(m, ls[j]);
    wv[t] = __expf(ls[t] - m);
  }
  __syncthreads();
  float ssum = 0.f;
  #pragma unroll
  for (int j = 0; j < TK; ++j) ssum += wv[j];
  float inv = 1.f / ssum;
  #pragma unroll
  for (int u = 0; u < 8; ++u) {
    int c = u * 64 + t;
    float acc = 0.f;
    #pragma unroll
    for (int k = 0; k < TK; ++k)
      acc = fmaf(wv[k] * inv, queue[(size_t)wid[k] * 512 + c], acc);
    neigh[(size_t)row * 512 + c] = acc;
  }
}

__global__ void gemm_n18_kernel(const float* __restrict__ Z, const float* __restrict__ W2,
    const float* __restrict__ b2, float* __restrict__ out, int Mrows)
{
  int o = blockIdx.x * 256 + threadIdx.x;
  if (o >= Mrows * 18) return;
  int r = o / 18, c = o - r * 18;
  const float* zp = Z + (size_t)r * 512;
  float acc = b2[c];
  #pragma unroll 8
  for (int k = 0; k < 512; ++k) acc = fmaf(zp[k], W2[k*18 + c], acc);
  out[o] = acc;
}

// ---------------------------------------------------------------------------
extern "C" void kernel_launch(void* const* d_in, const int* in_sizes, int n_in,
                              void* d_out, int out_size, void* d_ws, size_t ws_size,
                              hipStream_t stream)
{
  #define IN(i) ((const float*)d_in[i])
  const float* img_feat = IN(0);
  const float* option   = IN(1);
  const float* semantic = IN(2);
  const float* queue    = IN(3);
  const float* vae_w1 = IN(4);  const float* vae_b1 = IN(5);
  const float* vae_g1 = IN(6);  const float* vae_be1 = IN(7);
  const float* vae_w2 = IN(8);  const float* vae_b2 = IN(9);
  const float* opt_w1 = IN(10); const float* opt_b1 = IN(11);
  const float* opt_g1 = IN(12); const float* opt_be1 = IN(13);
  const float* opt_w2 = IN(14); const float* opt_b2 = IN(15);
  const float* opt_g2 = IN(16); const float* opt_be2 = IN(17);
  const float* sem_w1 = IN(18); const float* sem_b1 = IN(19);
  const float* sem_g1 = IN(20); const float* sem_be1 = IN(21);
  const float* sem_w2 = IN(22); const float* sem_b2 = IN(23);
  const float* sem_g2 = IN(24); const float* sem_be2 = IN(25);
  const float* fus_w = IN(26);  const float* fus_b = IN(27);
  const float* fus_g = IN(28);  const float* fus_be = IN(29);
  const float* fus_sg = IN(30); const float* fus_sb = IN(31);
  const float* cls_w1 = IN(32); const float* cls_b1 = IN(33);
  const float* cls_g = IN(34);  const float* cls_be = IN(35);
  const float* cls_w2 = IN(36); const float* cls_b2 = IN(37);

  float* ws = (float*)d_ws;
  size_t off = 0;
  auto alloc = [&](size_t n) { float* p = ws + off; off += (n + 255) & ~(size_t)255; return p; };

  const int srows = (ws_size >= (size_t)74 * 1024 * 1024) ? 256 : 128;

  float* S    = alloc((size_t)srows * 32768);
  float* H    = alloc(4 * 1024 * 512);
  float* Z4   = alloc(4 * 1024 * 512);
  float* zstart = ws + off;          // ---- region zeroed for split-K atomics ----
  float* t1   = alloc(1024 * 512);
  float* img  = alloc(1024 * 512);
  float* o1   = alloc(1024 * 192);
  float* optb = alloc(1024 * 512);
  float* s1   = alloc(1024 * 192);
  float* semb = alloc(1024 * 512);
  float* P    = alloc(3 * 1024 * 512);
  float* Z1   = alloc(1024 * 512);
  size_t zbytes = (size_t)((ws + off) - zstart) * 4;   // ---- end zero region ----
  float* neigh = alloc(1024 * 512);
  float* qn   = alloc(1024);
  float* kn   = alloc(32768);
  float* scv  = alloc(512);  float* shv  = alloc(512);
  float* sco1 = alloc(192);  float* sho1 = alloc(192);
  float* sco2 = alloc(512);  float* sho2 = alloc(512);
  float* scs1 = alloc(192);  float* shs1 = alloc(192);
  float* scs2 = alloc(512);  float* shs2 = alloc(512);
  float* scf  = alloc(4*512); float* shf = alloc(4*512);
  float* scc4 = alloc(4*512); float* shc4 = alloc(4*512);
  float* scc1 = alloc(512);  float* shc1 = alloc(512);
  float* g4   = alloc(4*512); float* b4  = alloc(4*512);
  float* topd2 = alloc(1024 * TK);
  int*   topidx = (int*)alloc(1024 * TK);

  hipMemsetAsync(zstart, 0, zbytes, stream);

  dim3 blk(256);
  // --- VAE branch
  gemm64_kernel<<<dim3(8,16,4), blk, 0, stream>>>(img_feat, vae_w1, vae_b1, t1, 1024, 512, 2048);
  bn_stats_kernel<<<dim3(8,1), blk, 0, stream>>>(t1, 512, vae_g1, vae_be1, 0, scv, shv);
  bn_apply_relu_kernel<<<dim3(512), blk, 0, stream>>>(t1, 512, scv, shv, 131072);
  gemm64_kernel<<<dim3(8,16,4), blk, 0, stream>>>(t1, vae_w2, vae_b2, img, 1024, 512, 512);
  // --- option encoder
  gemm64_kernel<<<dim3(3,16,8), blk, 0, stream>>>(option, opt_w1, opt_b1, o1, 1024, 192, 768);
  bn_stats_kernel<<<dim3(3,1), blk, 0, stream>>>(o1, 192, opt_g1, opt_be1, 0, sco1, sho1);
  bn_apply_relu_kernel<<<dim3(192), blk, 0, stream>>>(o1, 192, sco1, sho1, 49152);
  gemm64_kernel<<<dim3(8,16,2), blk, 0, stream>>>(o1, opt_w2, opt_b2, optb, 1024, 512, 192);
  bn_stats_kernel<<<dim3(8,1), blk, 0, stream>>>(optb, 512, opt_g2, opt_be2, 0, sco2, sho2);
  bn_apply_relu_kernel<<<dim3(512), blk, 0, stream>>>(optb, 512, sco2, sho2, 131072);
  // --- semantic encoder
  gemm64_kernel<<<dim3(3,16,8), blk, 0, stream>>>(semantic, sem_w1, sem_b1, s1, 1024, 192, 768);
  bn_stats_kernel<<<dim3(3,1), blk, 0, stream>>>(s1, 192, sem_g1, sem_be1, 0, scs1, shs1);
  bn_apply_relu_kernel<<<dim3(192), blk, 0, stream>>>(s1, 192, scs1, shs1, 49152);
  gemm64_kernel<<<dim3(8,16,2), blk, 0, stream>>>(s1, sem_w2, sem_b2, semb, 1024, 512, 192);
  bn_stats_kernel<<<dim3(8,1), blk, 0, stream>>>(semb, 512, sem_g2, sem_be2, 0, scs2, shs2);
  bn_apply_relu_kernel<<<dim3(512), blk, 0, stream>>>(semb, 512, scs2, shs2, 131072);
  // --- fusion
  gemm64_kernel<<<dim3(8,16,4), blk, 0, stream>>>(img,  fus_w,          nullptr, P,           1024, 512, 512);
  gemm64_kernel<<<dim3(8,16,4), blk, 0, stream>>>(optb, fus_w + 262144, nullptr, P + 524288,  1024, 512, 512);
  gemm64_kernel<<<dim3(8,16,4), blk, 0, stream>>>(semb, fus_w + 524288, nullptr, P + 1048576, 1024, 512, 512);
  fuse_combine_kernel<<<dim3(512), blk, 0, stream>>>(P, fus_w + 1536*512, fus_b, H);
  pack_gb_kernel<<<dim3(8), blk, 0, stream>>>(fus_sg, fus_sb, fus_g, fus_be, g4, b4);
  bn_stats_kernel<<<dim3(8,4), blk, 0, stream>>>(H, 512, g4, b4, 512, scf, shf);
  bn_apply_relu_kernel<<<dim3(2048), blk, 0, stream>>>(H, 512, scf, shf, 524288);
  // --- classifier on heads 0..3
  gemm64_kernel<<<dim3(8,64,1), blk, 0, stream>>>(H, cls_w1, cls_b1, Z4, 4096, 512, 512);
  bn_stats_kernel<<<dim3(8,4), blk, 0, stream>>>(Z4, 512, cls_g, cls_be, 0, scc4, shc4);
  bn_apply_relu_kernel<<<dim3(2048), blk, 0, stream>>>(Z4, 512, scc4, shc4, 524288);
  gemm_n18_kernel<<<dim3((4096*18 + 255)/256), blk, 0, stream>>>(Z4, cls_w2, cls_b2, (float*)d_out, 4096);
  // --- kNN retrieval: bf16-MFMA approx scores + exact fp32 rescue
  const float* fused = H + (size_t)3 * 1024 * 512;
  row_sumsq_kernel<<<dim3(256), blk, 0, stream>>>(fused, qn, 1024);
  row_sumsq_kernel<<<dim3(8192), blk, 0, stream>>>(queue, kn, 32768);
  for (int sbase = 0; sbase < 1024; sbase += srows) {
    score_mfma_kernel<<<dim3(256, srows/128), blk, 0, stream>>>(fused + (size_t)sbase*512, queue, S);
    topk_rescue_kernel<<<dim3(srows), blk, 0, stream>>>(S, fused, queue, qn, kn, sbase, topd2, topidx);
  }
  knn_gather_kernel<<<dim3(1024), dim3(64), 0, stream>>>(topd2, topidx, queue, neigh);
  // --- classifier on neigh (head 4)
  gemm64_kernel<<<dim3(8,16,4), blk, 0, stream>>>(neigh, cls_w1, cls_b1, Z1, 1024, 512, 512);
  bn_stats_kernel<<<dim3(8,1), blk, 0, stream>>>(Z1, 512, cls_g, cls_be, 0, scc1, shc1);
  bn_apply_relu_kernel<<<dim3(512), blk, 0, stream>>>(Z1, 512, scc1, shc1, 131072);
  gemm_n18_kernel<<<dim3((1024*18 + 255)/256), blk, 0, stream>>>(Z1, cls_w2, cls_b2, (float*)d_out + 4*1024*18, 1024);
  #undef IN
}

// Round 3
// 1069.093 us; speedup vs baseline: 1.4771x; 1.3163x over previous
//
#include <hip/hip_runtime.h>
#include <cstdint>
#include <cstddef>

#define TK 10

typedef unsigned short u16;
typedef __attribute__((ext_vector_type(8))) short short8;
typedef __attribute__((ext_vector_type(4))) float f32x4;

__device__ __forceinline__ float4 ld4(const float* p){ return *(const float4*)p; }

// fp32 -> bf16 round-to-nearest-even
__device__ __forceinline__ u16 bfr(float x){
  unsigned u = __float_as_uint(x);
  return (u16)((u + 0x7FFFu + ((u >> 16) & 1u)) >> 16);
}

// ---------------------------------------------------------------------------
// gemm64: C[M,N] = A[M,K] @ W[K,N] (+bias). Split-K over gridDim.z via atomicAdd
// (C must be pre-zeroed when gridDim.z > 1). Tile 64x64, BK=16, 4x4 microtile.
// ---------------------------------------------------------------------------
__global__ __launch_bounds__(256) void gemm64_kernel(const float* __restrict__ A,
    const float* __restrict__ W, const float* __restrict__ bias,
    float* __restrict__ C, int M, int N, int K)
{
  __shared__ float As[16][68];
  __shared__ float Bs[16][64];
  const int t  = threadIdx.x;
  const int n0 = blockIdx.x * 64;
  const int m0 = blockIdx.y * 64;
  const int kchunk = K / gridDim.z;
  const int kbeg = blockIdx.z * kchunk;
  const int tm = t >> 4, tn = t & 15;
  const int ar = t >> 2, ak = (t & 3) << 2;
  const int bk = t >> 4, bc = (t & 15) << 2;
  const float* Ap = A + (size_t)(m0 + ar) * K + kbeg + ak;
  const float* Wp = W + (size_t)(kbeg + bk) * N + n0 + bc;
  float acc[4][4] = {};
  for (int kt = 0; kt < kchunk; kt += 16) {
    float4 a4 = ld4(Ap); Ap += 16;
    float4 b4 = ld4(Wp); Wp += (size_t)16 * N;
    __syncthreads();
    As[ak+0][ar] = a4.x; As[ak+1][ar] = a4.y; As[ak+2][ar] = a4.z; As[ak+3][ar] = a4.w;
    *(float4*)&Bs[bk][bc] = b4;
    __syncthreads();
    #pragma unroll
    for (int k = 0; k < 16; ++k) {
      float4 av = ld4(&As[k][tm << 2]);
      float4 bv = ld4(&Bs[k][tn << 2]);
      const float aa[4] = {av.x, av.y, av.z, av.w};
      const float bb[4] = {bv.x, bv.y, bv.z, bv.w};
      #pragma unroll
      for (int i = 0; i < 4; ++i)
        #pragma unroll
        for (int j = 0; j < 4; ++j)
          acc[i][j] = fmaf(aa[i], bb[j], acc[i][j]);
    }
  }
  const int cn = n0 + (tn << 2);
  if (gridDim.z == 1) {
    float bx = bias ? bias[cn+0] : 0.f;
    float by = bias ? bias[cn+1] : 0.f;
    float bz = bias ? bias[cn+2] : 0.f;
    float bw = bias ? bias[cn+3] : 0.f;
    #pragma unroll
    for (int i = 0; i < 4; ++i) {
      int m = m0 + (tm << 2) + i;
      float4 o = { acc[i][0]+bx, acc[i][1]+by, acc[i][2]+bz, acc[i][3]+bw };
      *(float4*)&C[(size_t)m * N + cn] = o;
    }
  } else {
    float badd[4] = {0.f, 0.f, 0.f, 0.f};
    if (bias && blockIdx.z == 0) {
      badd[0]=bias[cn]; badd[1]=bias[cn+1]; badd[2]=bias[cn+2]; badd[3]=bias[cn+3];
    }
    #pragma unroll
    for (int i = 0; i < 4; ++i) {
      int m = m0 + (tm << 2) + i;
      #pragma unroll
      for (int j = 0; j < 4; ++j)
        atomicAdd(&C[(size_t)m * N + cn + j], acc[i][j] + badd[j]);
    }
  }
}

// ---------------------------------------------------------------------------
// score_mfma: C[Mt,32768] = A[Mt,512] @ queue[32768,512]^T in bf16 MFMA,
// fp32 accumulate. In-register fp32->bf16 cvt during LDS staging.
// Block 256 thr = 4 waves (2x2), tile 128x128, BK=64, 16x16x32 MFMA.
// LDS XOR swizzle on 16B chunks: phys_chunk = row*8 + (c ^ (row&7)).
// ---------------------------------------------------------------------------
__global__ __launch_bounds__(256) void score_mfma_kernel(
    const float* __restrict__ A, const float* __restrict__ Bq,
    float* __restrict__ C)
{
  __shared__ u16 At[128 * 64];
  __shared__ u16 Bt[128 * 64];
  const int t  = threadIdx.x;
  const int n0 = blockIdx.x * 128;
  const int m0 = blockIdx.y * 128;

  u16* ldsA[4]; u16* ldsB[4];
  const float* gA[4]; const float* gB[4];
  #pragma unroll
  for (int i = 0; i < 4; ++i) {
    int L = i * 256 + t;
    int row = L >> 3, c = L & 7;
    int phys = row * 8 + (c ^ (row & 7));
    ldsA[i] = &At[phys * 8]; ldsB[i] = &Bt[phys * 8];
    gA[i] = A  + (size_t)(m0 + row) * 512 + c * 8;
    gB[i] = Bq + (size_t)(n0 + row) * 512 + c * 8;
  }

  const int lane = t & 63, w = t >> 6;
  const int wm = (w >> 1) * 64, wn = (w & 1) * 64;
  const int q = lane >> 4, rl = lane & 15;

  f32x4 acc[4][4];
  const f32x4 z4 = {0.f, 0.f, 0.f, 0.f};
  #pragma unroll
  for (int i = 0; i < 4; ++i)
    #pragma unroll
    for (int j = 0; j < 4; ++j) acc[i][j] = z4;

  union U16x8 { u16 u[8]; float4 f4; };

  for (int k0 = 0; k0 < 512; k0 += 64) {
    float4 ra[4][2], rb[4][2];
    #pragma unroll
    for (int i = 0; i < 4; ++i) {
      ra[i][0] = ld4(gA[i]); ra[i][1] = ld4(gA[i] + 4);
      rb[i][0] = ld4(gB[i]); rb[i][1] = ld4(gB[i] + 4);
      gA[i] += 64; gB[i] += 64;
    }
    __syncthreads();
    #pragma unroll
    for (int i = 0; i < 4; ++i) {
      U16x8 pa, pb;
      pa.u[0]=bfr(ra[i][0].x); pa.u[1]=bfr(ra[i][0].y); pa.u[2]=bfr(ra[i][0].z); pa.u[3]=bfr(ra[i][0].w);
      pa.u[4]=bfr(ra[i][1].x); pa.u[5]=bfr(ra[i][1].y); pa.u[6]=bfr(ra[i][1].z); pa.u[7]=bfr(ra[i][1].w);
      pb.u[0]=bfr(rb[i][0].x); pb.u[1]=bfr(rb[i][0].y); pb.u[2]=bfr(rb[i][0].z); pb.u[3]=bfr(rb[i][0].w);
      pb.u[4]=bfr(rb[i][1].x); pb.u[5]=bfr(rb[i][1].y); pb.u[6]=bfr(rb[i][1].z); pb.u[7]=bfr(rb[i][1].w);
      *(float4*)ldsA[i] = pa.f4;
      *(float4*)ldsB[i] = pb.f4;
    }
    __syncthreads();
    #pragma unroll
    for (int kk = 0; kk < 2; ++kk) {
      short8 af[4], bfv[4];
      #pragma unroll
      for (int mt = 0; mt < 4; ++mt) {
        int r = wm + mt * 16 + rl;
        int cc = (kk * 4 + q) ^ (r & 7);
        af[mt] = *(const short8*)&At[(r * 8 + cc) * 8];
      }
      #pragma unroll
      for (int nt = 0; nt < 4; ++nt) {
        int r = wn + nt * 16 + rl;
        int cc = (kk * 4 + q) ^ (r & 7);
        bfv[nt] = *(const short8*)&Bt[(r * 8 + cc) * 8];
      }
      #pragma unroll
      for (int mt = 0; mt < 4; ++mt)
        #pragma unroll
        for (int nt = 0; nt < 4; ++nt)
          acc[mt][nt] = __builtin_amdgcn_mfma_f32_16x16x32_bf16(af[mt], bfv[nt], acc[mt][nt], 0, 0, 0);
    }
  }
  // epilogue: C/D layout col = lane&15, row = q*4 + reg  [m89-verified]
  #pragma unroll
  for (int mt = 0; mt < 4; ++mt)
    #pragma unroll
    for (int nt = 0; nt < 4; ++nt) {
      int m = m0 + wm + mt * 16 + q * 4;
      int n = n0 + wn + nt * 16 + rl;
      #pragma unroll
      for (int reg = 0; reg < 4; ++reg)
        C[(size_t)(m + reg) * 32768 + n] = acc[mt][nt][reg];
    }
}

// ---------------------------------------------------------------------------
// BN column stats over 1024 rows -> scale/shift.
// ---------------------------------------------------------------------------
__global__ __launch_bounds__(256) void bn_stats_kernel(const float* __restrict__ X, int N,
    const float* __restrict__ gamma, const float* __restrict__ beta, int gstride,
    float* __restrict__ scale, float* __restrict__ shift)
{
  const int head = blockIdx.y;
  const float* Xh = X + (size_t)head * 1024 * N;
  const int lane = threadIdx.x & 63;
  const int col  = blockIdx.x * 64 + lane;
  const int rg   = threadIdx.x >> 6;
  float s = 0.f, ss = 0.f;
  const float* p = Xh + (size_t)(rg * 256) * N + col;
  for (int rr = 0; rr < 256; ++rr) { float v = *p; p += N; s += v; ss = fmaf(v, v, ss); }
  __shared__ float Ssum[4][64], Ssq[4][64];
  Ssum[rg][lane] = s; Ssq[rg][lane] = ss;
  __syncthreads();
  if (threadIdx.x < 64) {
    s  = Ssum[0][lane] + Ssum[1][lane] + Ssum[2][lane] + Ssum[3][lane];
    ss = Ssq[0][lane]  + Ssq[1][lane]  + Ssq[2][lane]  + Ssq[3][lane];
    float mean = s * (1.f / 1024.f);
    float var  = ss * (1.f / 1024.f) - mean * mean;
    float sc   = gamma[head * gstride + col] / sqrtf(var + 1e-5f);
    scale[head * N + col] = sc;
    shift[head * N + col] = beta[head * gstride + col] - mean * sc;
  }
}

__global__ void bn_apply_relu_kernel(float* __restrict__ X, int N,
    const float* __restrict__ scale, const float* __restrict__ shift, int total4)
{
  int i = blockIdx.x * 256 + threadIdx.x;
  if (i >= total4) return;
  size_t base = (size_t)i * 4;
  int col  = (int)(base % (size_t)N);
  int head = (int)(base / ((size_t)1024 * N));
  int sb = head * N + col;
  float4 v = *(float4*)&X[base];
  v.x = fmaxf(0.f, fmaf(v.x, scale[sb+0], shift[sb+0]));
  v.y = fmaxf(0.f, fmaf(v.y, scale[sb+1], shift[sb+1]));
  v.z = fmaxf(0.f, fmaf(v.z, scale[sb+2], shift[sb+2]));
  v.w = fmaxf(0.f, fmaf(v.w, scale[sb+3], shift[sb+3]));
  *(float4*)&X[base] = v;
}

__global__ void fuse_combine_kernel(const float* __restrict__ P,
    const float* __restrict__ fwr, const float* __restrict__ fb, float* __restrict__ H)
{
  int i = blockIdx.x * 256 + threadIdx.x;
  if (i >= 131072) return;
  size_t base = (size_t)i * 4;
  int c = (int)(base & 511);
  float4 p0 = ld4(P + base), p1 = ld4(P + 524288 + base), p2 = ld4(P + 1048576 + base);
  float4 w0 = ld4(fwr + c), w1 = ld4(fwr + 512 + c), w2 = ld4(fwr + 1024 + c), b = ld4(fb + c);
  float4 h0, h1, h2, h3;
  h0.x=p0.x+w0.x+b.x; h0.y=p0.y+w0.y+b.y; h0.z=p0.z+w0.z+b.z; h0.w=p0.w+w0.w+b.w;
  h1.x=p1.x+w1.x+b.x; h1.y=p1.y+w1.y+b.y; h1.z=p1.z+w1.z+b.z; h1.w=p1.w+w1.w+b.w;
  h2.x=p2.x+w2.x+b.x; h2.y=p2.y+w2.y+b.y; h2.z=p2.z+w2.z+b.z; h2.w=p2.w+w2.w+b.w;
  h3.x=p0.x+p1.x+p2.x+w0.x+w1.x+w2.x+b.x;
  h3.y=p0.y+p1.y+p2.y+w0.y+w1.y+w2.y+b.y;
  h3.z=p0.z+p1.z+p2.z+w0.z+w1.z+w2.z+b.z;
  h3.w=p0.w+p1.w+p2.w+w0.w+w1.w+w2.w+b.w;
  *(float4*)&H[base]           = h0;
  *(float4*)&H[524288 + base]  = h1;
  *(float4*)&H[1048576 + base] = h2;
  *(float4*)&H[1572864 + base] = h3;
}

__global__ void pack_gb_kernel(const float* __restrict__ sg, const float* __restrict__ sb,
    const float* __restrict__ g, const float* __restrict__ be,
    float* __restrict__ g4, float* __restrict__ b4)
{
  int i = blockIdx.x * 256 + threadIdx.x;
  if (i < 1536)      { g4[i] = sg[i];      b4[i] = sb[i]; }
  else if (i < 2048) { g4[i] = g[i-1536];  b4[i] = be[i-1536]; }
}

__global__ void row_sumsq_kernel(const float* __restrict__ X, float* __restrict__ out, int nrows)
{
  int row  = blockIdx.x * 4 + (threadIdx.x >> 6);
  int lane = threadIdx.x & 63;
  if (row >= nrows) return;
  const float* p = X + (size_t)row * 512 + lane * 8;
  float4 a = ld4(p), b = ld4(p + 4);
  float s = a.x*a.x + a.y*a.y + a.z*a.z + a.w*a.w
          + b.x*b.x + b.y*b.y + b.z*b.z + b.w*b.w;
  for (int off = 32; off; off >>= 1) s += __shfl_down(s, off, 64);
  if (lane == 0) out[row] = s;
}

// ---------------------------------------------------------------------------
// topk_rescue v2: 512 thr/block, one block per stripe row.
// Phase 1: per-thread register-sorted top-6 over 64 cols (approx d2).
// Phase 2: 16 rounds of head-only argmin (shuffle + 8-entry LDS broadcast) ->
//          approx top-16 candidate indices. No list LDS -> no bank conflicts.
// Phase 3: exact fp32 d2 for 16 candidates (32 thr each, global reads).
// Phase 4: exact lexicographic top-10 of 16 (wave 0).
// ---------------------------------------------------------------------------
__global__ __launch_bounds__(512) void topk_rescue_kernel(const float* __restrict__ S,
    const float* __restrict__ fusedF, const float* __restrict__ queue,
    const float* __restrict__ qn, const float* __restrict__ kn, int rowbase,
    float* __restrict__ topd2, int* __restrict__ topidx)
{
  const int row  = blockIdx.x;
  const int grow = rowbase + row;
  const float* Srow = S + (size_t)row * 32768;
  const float qnr = qn[grow];
  const int t = threadIdx.x;
  const float INF = __builtin_inff();

  // phase 1
  float vals[6]; int idxs[6];
  #pragma unroll
  for (int j = 0; j < 6; ++j) { vals[j] = INF; idxs[j] = 0x7fffffff; }
  for (int q = t; q < 32768; q += 512) {
    float d2 = (qnr + kn[q]) - 2.f * Srow[q];
    if (d2 < vals[5]) {
      float cv = d2; int ci = q;
      #pragma unroll
      for (int j = 0; j < 6; ++j) {
        bool less = (cv < vals[j]) || (cv == vals[j] && ci < idxs[j]);
        float tv = less ? vals[j] : cv; int ti = less ? idxs[j] : ci;
        vals[j] = less ? cv : vals[j]; idxs[j] = less ? ci : idxs[j];
        cv = tv; ci = ti;
      }
    }
  }

  // phase 2
  __shared__ float Wv[8]; __shared__ int Wi[8];
  __shared__ int   Ci[16]; __shared__ float Cd[16];
  const int lane = t & 63, wid = t >> 6;
  for (int sel = 0; sel < 16; ++sel) {
    float bv = vals[0]; int bi = idxs[0];
    #pragma unroll
    for (int off = 32; off >= 1; off >>= 1) {
      float ov = __shfl_down(bv, off, 64);
      int   oi = __shfl_down(bi, off, 64);
      if (ov < bv || (ov == bv && oi < bi)) { bv = ov; bi = oi; }
    }
    if (lane == 0) { Wv[wid] = bv; Wi[wid] = bi; }
    __syncthreads();
    float gv = Wv[0]; int gi = Wi[0];
    #pragma unroll
    for (int w2 = 1; w2 < 8; ++w2) {
      float wv2 = Wv[w2]; int wi2 = Wi[w2];
      if (wv2 < gv || (wv2 == gv && wi2 < gi)) { gv = wv2; gi = wi2; }
    }
    if (t == 0) Ci[sel] = gi;
    if (vals[0] == gv && idxs[0] == gi) {   // unique winner pops its head
      #pragma unroll
      for (int j = 0; j < 5; ++j) { vals[j] = vals[j+1]; idxs[j] = idxs[j+1]; }
      vals[5] = INF; idxs[5] = 0x7fffffff;
    }
    __syncthreads();
  }

  // phase 3: exact fp32 d2, 32 threads per candidate
  {
    int c = t >> 5, s = t & 31;
    int qi = Ci[c];
    const float* qp = queue  + (size_t)qi * 512 + s * 16;
    const float* fp = fusedF + (size_t)grow * 512 + s * 16;
    float dot = 0.f;
    #pragma unroll
    for (int j = 0; j < 4; ++j) {
      float4 a = ld4(fp + j*4); float4 b = ld4(qp + j*4);
      dot += a.x*b.x + a.y*b.y + a.z*b.z + a.w*b.w;
    }
    #pragma unroll
    for (int off = 16; off >= 1; off >>= 1) dot += __shfl_down(dot, off, 32);
    if (s == 0) Cd[c] = qnr + kn[qi] - 2.f * dot;
  }
  __syncthreads();

  // phase 4: exact lexicographic top-10 of 16 (wave 0)
  if (t < 64) {
    float v = (t < 16) ? Cd[t] : INF;
    int  id = (t < 16) ? Ci[t] : 0x7fffffff;
    for (int sel = 0; sel < TK; ++sel) {
      float bv = v; int bi = id;
      #pragma unroll
      for (int off = 32; off >= 1; off >>= 1) {
        float ov = __shfl_down(bv, off, 64);
        int   oi = __shfl_down(bi, off, 64);
        if (ov < bv || (ov == bv && oi < bi)) { bv = ov; bi = oi; }
      }
      bv = __shfl(bv, 0, 64); bi = __shfl(bi, 0, 64);
      if (t == 0) { topd2[grow*TK + sel] = bv; topidx[grow*TK + sel] = bi; }
      if (id == bi) { v = INF; id = 0x7fffffff; }
    }
  }
}

__global__ void knn_gather_kernel(const float* __restrict__ topd2, const int* __restrict__ topidx,
    const float* __restrict__ queue, float* __restrict__ neigh)
{
  const int row = blockIdx.x;
  const int t = threadIdx.x;   // 64
  __shared__ float ls[TK]; __shared__ float wv[TK]; __shared__ int wid[TK];
  if (t < TK) {
    float d = sqrtf(fmaxf(topd2[row*TK + t], 0.f));
    ls[t]  = -d / 0.07f;
    wid[t] = topidx[row*TK + t];
  }
  __syncthreads();
  if (t < TK) {
    float m = ls[0];
    #pragma unroll
    for (int j = 1; j < TK; ++j) m = fmaxf(m, ls[j]);
    wv[t] = __expf(ls[t] - m);
  }
  __syncthreads();
  float ssum = 0.f;
  #pragma unroll
  for (int j = 0; j < TK; ++j) ssum += wv[j];
  float inv = 1.f / ssum;
  #pragma unroll
  for (int u = 0; u < 8; ++u) {
    int c = u * 64 + t;
    float acc = 0.f;
    #pragma unroll
    for (int k = 0; k < TK; ++k)
      acc = fmaf(wv[k] * inv, queue[(size_t)wid[k] * 512 + c], acc);
    neigh[(size_t)row * 512 + c] = acc;
  }
}

__global__ void gemm_n18_kernel(const float* __restrict__ Z, const float* __restrict__ W2,
    const float* __restrict__ b2, float* __restrict__ out, int Mrows)
{
  int o = blockIdx.x * 256 + threadIdx.x;
  if (o >= Mrows * 18) return;
  int r = o / 18, c = o - r * 18;
  const float* zp = Z + (size_t)r * 512;
  float acc = b2[c];
  #pragma unroll 8
  for (int k = 0; k < 512; ++k) acc = fmaf(zp[k], W2[k*18 + c], acc);
  out[o] = acc;
}

// ---------------------------------------------------------------------------
extern "C" void kernel_launch(void* const* d_in, const int* in_sizes, int n_in,
                              void* d_out, int out_size, void* d_ws, size_t ws_size,
                              hipStream_t stream)
{
  #define IN(i) ((const float*)d_in[i])
  const float* img_feat = IN(0);
  const float* option   = IN(1);
  const float* semantic = IN(2);
  const float* queue    = IN(3);
  const float* vae_w1 = IN(4);  const float* vae_b1 = IN(5);
  const float* vae_g1 = IN(6);  const float* vae_be1 = IN(7);
  const float* vae_w2 = IN(8);  const float* vae_b2 = IN(9);
  const float* opt_w1 = IN(10); const float* opt_b1 = IN(11);
  const float* opt_g1 = IN(12); const float* opt_be1 = IN(13);
  const float* opt_w2 = IN(14); const float* opt_b2 = IN(15);
  const float* opt_g2 = IN(16); const float* opt_be2 = IN(17);
  const float* sem_w1 = IN(18); const float* sem_b1 = IN(19);
  const float* sem_g1 = IN(20); const float* sem_be1 = IN(21);
  const float* sem_w2 = IN(22); const float* sem_b2 = IN(23);
  const float* sem_g2 = IN(24); const float* sem_be2 = IN(25);
  const float* fus_w = IN(26);  const float* fus_b = IN(27);
  const float* fus_g = IN(28);  const float* fus_be = IN(29);
  const float* fus_sg = IN(30); const float* fus_sb = IN(31);
  const float* cls_w1 = IN(32); const float* cls_b1 = IN(33);
  const float* cls_g = IN(34);  const float* cls_be = IN(35);
  const float* cls_w2 = IN(36); const float* cls_b2 = IN(37);

  float* ws = (float*)d_ws;
  size_t off = 0;
  auto alloc = [&](size_t n) { float* p = ws + off; off += (n + 255) & ~(size_t)255; return p; };

  const int srows = (ws_size >= (size_t)74 * 1024 * 1024) ? 256 : 128;

  float* S    = alloc((size_t)srows * 32768);
  float* H    = alloc(4 * 1024 * 512);
  float* Z4   = alloc(4 * 1024 * 512);
  float* zstart = ws + off;          // ---- region zeroed for split-K atomics ----
  float* t1   = alloc(1024 * 512);
  float* img  = alloc(1024 * 512);
  float* o1   = alloc(1024 * 192);
  float* optb = alloc(1024 * 512);
  float* s1   = alloc(1024 * 192);
  float* semb = alloc(1024 * 512);
  float* P    = alloc(3 * 1024 * 512);
  float* Z1   = alloc(1024 * 512);
  size_t zbytes = (size_t)((ws + off) - zstart) * 4;   // ---- end zero region ----
  float* neigh = alloc(1024 * 512);
  float* qn   = alloc(1024);
  float* kn   = alloc(32768);
  float* scv  = alloc(512);  float* shv  = alloc(512);
  float* sco1 = alloc(192);  float* sho1 = alloc(192);
  float* sco2 = alloc(512);  float* sho2 = alloc(512);
  float* scs1 = alloc(192);  float* shs1 = alloc(192);
  float* scs2 = alloc(512);  float* shs2 = alloc(512);
  float* scf  = alloc(4*512); float* shf = alloc(4*512);
  float* scc4 = alloc(4*512); float* shc4 = alloc(4*512);
  float* scc1 = alloc(512);  float* shc1 = alloc(512);
  float* g4   = alloc(4*512); float* b4  = alloc(4*512);
  float* topd2 = alloc(1024 * TK);
  int*   topidx = (int*)alloc(1024 * TK);

  hipMemsetAsync(zstart, 0, zbytes, stream);

  dim3 blk(256);
  // --- VAE branch
  gemm64_kernel<<<dim3(8,16,4), blk, 0, stream>>>(img_feat, vae_w1, vae_b1, t1, 1024, 512, 2048);
  bn_stats_kernel<<<dim3(8,1), blk, 0, stream>>>(t1, 512, vae_g1, vae_be1, 0, scv, shv);
  bn_apply_relu_kernel<<<dim3(512), blk, 0, stream>>>(t1, 512, scv, shv, 131072);
  gemm64_kernel<<<dim3(8,16,4), blk, 0, stream>>>(t1, vae_w2, vae_b2, img, 1024, 512, 512);
  // --- option encoder
  gemm64_kernel<<<dim3(3,16,8), blk, 0, stream>>>(option, opt_w1, opt_b1, o1, 1024, 192, 768);
  bn_stats_kernel<<<dim3(3,1), blk, 0, stream>>>(o1, 192, opt_g1, opt_be1, 0, sco1, sho1);
  bn_apply_relu_kernel<<<dim3(192), blk, 0, stream>>>(o1, 192, sco1, sho1, 49152);
  gemm64_kernel<<<dim3(8,16,2), blk, 0, stream>>>(o1, opt_w2, opt_b2, optb, 1024, 512, 192);
  bn_stats_kernel<<<dim3(8,1), blk, 0, stream>>>(optb, 512, opt_g2, opt_be2, 0, sco2, sho2);
  bn_apply_relu_kernel<<<dim3(512), blk, 0, stream>>>(optb, 512, sco2, sho2, 131072);
  // --- semantic encoder
  gemm64_kernel<<<dim3(3,16,8), blk, 0, stream>>>(semantic, sem_w1, sem_b1, s1, 1024, 192, 768);
  bn_stats_kernel<<<dim3(3,1), blk, 0, stream>>>(s1, 192, sem_g1, sem_be1, 0, scs1, shs1);
  bn_apply_relu_kernel<<<dim3(192), blk, 0, stream>>>(s1, 192, scs1, shs1, 49152);
  gemm64_kernel<<<dim3(8,16,2), blk, 0, stream>>>(s1, sem_w2, sem_b2, semb, 1024, 512, 192);
  bn_stats_kernel<<<dim3(8,1), blk, 0, stream>>>(semb, 512, sem_g2, sem_be2, 0, scs2, shs2);
  bn_apply_relu_kernel<<<dim3(512), blk, 0, stream>>>(semb, 512, scs2, shs2, 131072);
  // --- fusion
  gemm64_kernel<<<dim3(8,16,4), blk, 0, stream>>>(img,  fus_w,          nullptr, P,           1024, 512, 512);
  gemm64_kernel<<<dim3(8,16,4), blk, 0, stream>>>(optb, fus_w + 262144, nullptr, P + 524288,  1024, 512, 512);
  gemm64_kernel<<<dim3(8,16,4), blk, 0, stream>>>(semb, fus_w + 524288, nullptr, P + 1048576, 1024, 512, 512);
  fuse_combine_kernel<<<dim3(512), blk, 0, stream>>>(P, fus_w + 1536*512, fus_b, H);
  pack_gb_kernel<<<dim3(8), blk, 0, stream>>>(fus_sg, fus_sb, fus_g, fus_be, g4, b4);
  bn_stats_kernel<<<dim3(8,4), blk, 0, stream>>>(H, 512, g4, b4, 512, scf, shf);
  bn_apply_relu_kernel<<<dim3(2048), blk, 0, stream>>>(H, 512, scf, shf, 524288);
  // --- classifier on heads 0..3
  gemm64_kernel<<<dim3(8,64,1), blk, 0, stream>>>(H, cls_w1, cls_b1, Z4, 4096, 512, 512);
  bn_stats_kernel<<<dim3(8,4), blk, 0, stream>>>(Z4, 512, cls_g, cls_be, 0, scc4, shc4);
  bn_apply_relu_kernel<<<dim3(2048), blk, 0, stream>>>(Z4, 512, scc4, shc4, 524288);
  gemm_n18_kernel<<<dim3((4096*18 + 255)/256), blk, 0, stream>>>(Z4, cls_w2, cls_b2, (float*)d_out, 4096);
  // --- kNN retrieval: bf16-MFMA approx scores + exact fp32 rescue
  const float* fused = H + (size_t)3 * 1024 * 512;
  row_sumsq_kernel<<<dim3(256), blk, 0, stream>>>(fused, qn, 1024);
  row_sumsq_kernel<<<dim3(8192), blk, 0, stream>>>(queue, kn, 32768);
  for (int sbase = 0; sbase < 1024; sbase += srows) {
    score_mfma_kernel<<<dim3(256, srows/128), blk, 0, stream>>>(fused + (size_t)sbase*512, queue, S);
    topk_rescue_kernel<<<dim3(srows), dim3(512), 0, stream>>>(S, fused, queue, qn, kn, sbase, topd2, topidx);
  }
  knn_gather_kernel<<<dim3(1024), dim3(64), 0, stream>>>(topd2, topidx, queue, neigh);
  // --- classifier on neigh (head 4)
  gemm64_kernel<<<dim3(8,16,4), blk, 0, stream>>>(neigh, cls_w1, cls_b1, Z1, 1024, 512, 512);
  bn_stats_kernel<<<dim3(8,1), blk, 0, stream>>>(Z1, 512, cls_g, cls_be, 0, scc1, shc1);
  bn_apply_relu_kernel<<<dim3(512), blk, 0, stream>>>(Z1, 512, scc1, shc1, 131072);
  gemm_n18_kernel<<<dim3((1024*18 + 255)/256), blk, 0, stream>>>(Z1, cls_w2, cls_b2, (float*)d_out + 4*1024*18, 1024);
  #undef IN
}

// Round 4
// 958.246 us; speedup vs baseline: 1.6480x; 1.1157x over previous
//
#include <hip/hip_runtime.h>
#include <cstdint>
#include <cstddef>

#define TK 10

typedef unsigned short u16;
typedef __attribute__((ext_vector_type(8))) short short8;
typedef __attribute__((ext_vector_type(4))) float f32x4;

__device__ __forceinline__ float4 ld4(const float* p){ return *(const float4*)p; }

// fp32 -> bf16 round-to-nearest-even
__device__ __forceinline__ u16 bfr(float x){
  unsigned u = __float_as_uint(x);
  return (u16)((u + 0x7FFFu + ((u >> 16) & 1u)) >> 16);
}

// ---------------------------------------------------------------------------
// gemm64: C[M,N] = A[M,K] @ W[K,N] (+bias). Split-K over gridDim.z via atomicAdd
// (C must be pre-zeroed when gridDim.z > 1). Tile 64x64, BK=16, 4x4 microtile.
// ---------------------------------------------------------------------------
__global__ __launch_bounds__(256) void gemm64_kernel(const float* __restrict__ A,
    const float* __restrict__ W, const float* __restrict__ bias,
    float* __restrict__ C, int M, int N, int K)
{
  __shared__ float As[16][68];
  __shared__ float Bs[16][64];
  const int t  = threadIdx.x;
  const int n0 = blockIdx.x * 64;
  const int m0 = blockIdx.y * 64;
  const int kchunk = K / gridDim.z;
  const int kbeg = blockIdx.z * kchunk;
  const int tm = t >> 4, tn = t & 15;
  const int ar = t >> 2, ak = (t & 3) << 2;
  const int bk = t >> 4, bc = (t & 15) << 2;
  const float* Ap = A + (size_t)(m0 + ar) * K + kbeg + ak;
  const float* Wp = W + (size_t)(kbeg + bk) * N + n0 + bc;
  float acc[4][4] = {};
  for (int kt = 0; kt < kchunk; kt += 16) {
    float4 a4 = ld4(Ap); Ap += 16;
    float4 b4 = ld4(Wp); Wp += (size_t)16 * N;
    __syncthreads();
    As[ak+0][ar] = a4.x; As[ak+1][ar] = a4.y; As[ak+2][ar] = a4.z; As[ak+3][ar] = a4.w;
    *(float4*)&Bs[bk][bc] = b4;
    __syncthreads();
    #pragma unroll
    for (int k = 0; k < 16; ++k) {
      float4 av = ld4(&As[k][tm << 2]);
      float4 bv = ld4(&Bs[k][tn << 2]);
      const float aa[4] = {av.x, av.y, av.z, av.w};
      const float bb[4] = {bv.x, bv.y, bv.z, bv.w};
      #pragma unroll
      for (int i = 0; i < 4; ++i)
        #pragma unroll
        for (int j = 0; j < 4; ++j)
          acc[i][j] = fmaf(aa[i], bb[j], acc[i][j]);
    }
  }
  const int cn = n0 + (tn << 2);
  if (gridDim.z == 1) {
    float bx = bias ? bias[cn+0] : 0.f;
    float by = bias ? bias[cn+1] : 0.f;
    float bz = bias ? bias[cn+2] : 0.f;
    float bw = bias ? bias[cn+3] : 0.f;
    #pragma unroll
    for (int i = 0; i < 4; ++i) {
      int m = m0 + (tm << 2) + i;
      float4 o = { acc[i][0]+bx, acc[i][1]+by, acc[i][2]+bz, acc[i][3]+bw };
      *(float4*)&C[(size_t)m * N + cn] = o;
    }
  } else {
    float badd[4] = {0.f, 0.f, 0.f, 0.f};
    if (bias && blockIdx.z == 0) {
      badd[0]=bias[cn]; badd[1]=bias[cn+1]; badd[2]=bias[cn+2]; badd[3]=bias[cn+3];
    }
    #pragma unroll
    for (int i = 0; i < 4; ++i) {
      int m = m0 + (tm << 2) + i;
      #pragma unroll
      for (int j = 0; j < 4; ++j)
        atomicAdd(&C[(size_t)m * N + cn + j], acc[i][j] + badd[j]);
    }
  }
}

// ---------------------------------------------------------------------------
// score_mfma: C[Mt,32768] = A[Mt,512] @ queue[32768,512]^T in bf16 MFMA,
// fp32 accumulate. In-register fp32->bf16 cvt during LDS staging.
// Block 256 thr = 4 waves (2x2), tile 128x128, BK=64, 16x16x32 MFMA.
// LDS XOR swizzle on 16B chunks: phys_chunk = row*8 + (c ^ (row&7)).
// ---------------------------------------------------------------------------
__global__ __launch_bounds__(256) void score_mfma_kernel(
    const float* __restrict__ A, const float* __restrict__ Bq,
    float* __restrict__ C)
{
  __shared__ u16 At[128 * 64];
  __shared__ u16 Bt[128 * 64];
  const int t  = threadIdx.x;
  const int n0 = blockIdx.x * 128;
  const int m0 = blockIdx.y * 128;

  u16* ldsA[4]; u16* ldsB[4];
  const float* gA[4]; const float* gB[4];
  #pragma unroll
  for (int i = 0; i < 4; ++i) {
    int L = i * 256 + t;
    int row = L >> 3, c = L & 7;
    int phys = row * 8 + (c ^ (row & 7));
    ldsA[i] = &At[phys * 8]; ldsB[i] = &Bt[phys * 8];
    gA[i] = A  + (size_t)(m0 + row) * 512 + c * 8;
    gB[i] = Bq + (size_t)(n0 + row) * 512 + c * 8;
  }

  const int lane = t & 63, w = t >> 6;
  const int wm = (w >> 1) * 64, wn = (w & 1) * 64;
  const int q = lane >> 4, rl = lane & 15;

  f32x4 acc[4][4];
  const f32x4 z4 = {0.f, 0.f, 0.f, 0.f};
  #pragma unroll
  for (int i = 0; i < 4; ++i)
    #pragma unroll
    for (int j = 0; j < 4; ++j) acc[i][j] = z4;

  union U16x8 { u16 u[8]; float4 f4; };

  for (int k0 = 0; k0 < 512; k0 += 64) {
    float4 ra[4][2], rb[4][2];
    #pragma unroll
    for (int i = 0; i < 4; ++i) {
      ra[i][0] = ld4(gA[i]); ra[i][1] = ld4(gA[i] + 4);
      rb[i][0] = ld4(gB[i]); rb[i][1] = ld4(gB[i] + 4);
      gA[i] += 64; gB[i] += 64;
    }
    __syncthreads();
    #pragma unroll
    for (int i = 0; i < 4; ++i) {
      U16x8 pa, pb;
      pa.u[0]=bfr(ra[i][0].x); pa.u[1]=bfr(ra[i][0].y); pa.u[2]=bfr(ra[i][0].z); pa.u[3]=bfr(ra[i][0].w);
      pa.u[4]=bfr(ra[i][1].x); pa.u[5]=bfr(ra[i][1].y); pa.u[6]=bfr(ra[i][1].z); pa.u[7]=bfr(ra[i][1].w);
      pb.u[0]=bfr(rb[i][0].x); pb.u[1]=bfr(rb[i][0].y); pb.u[2]=bfr(rb[i][0].z); pb.u[3]=bfr(rb[i][0].w);
      pb.u[4]=bfr(rb[i][1].x); pb.u[5]=bfr(rb[i][1].y); pb.u[6]=bfr(rb[i][1].z); pb.u[7]=bfr(rb[i][1].w);
      *(float4*)ldsA[i] = pa.f4;
      *(float4*)ldsB[i] = pb.f4;
    }
    __syncthreads();
    #pragma unroll
    for (int kk = 0; kk < 2; ++kk) {
      short8 af[4], bfv[4];
      #pragma unroll
      for (int mt = 0; mt < 4; ++mt) {
        int r = wm + mt * 16 + rl;
        int cc = (kk * 4 + q) ^ (r & 7);
        af[mt] = *(const short8*)&At[(r * 8 + cc) * 8];
      }
      #pragma unroll
      for (int nt = 0; nt < 4; ++nt) {
        int r = wn + nt * 16 + rl;
        int cc = (kk * 4 + q) ^ (r & 7);
        bfv[nt] = *(const short8*)&Bt[(r * 8 + cc) * 8];
      }
      #pragma unroll
      for (int mt = 0; mt < 4; ++mt)
        #pragma unroll
        for (int nt = 0; nt < 4; ++nt)
          acc[mt][nt] = __builtin_amdgcn_mfma_f32_16x16x32_bf16(af[mt], bfv[nt], acc[mt][nt], 0, 0, 0);
    }
  }
  // epilogue: C/D layout col = lane&15, row = q*4 + reg  [m89-verified]
  #pragma unroll
  for (int mt = 0; mt < 4; ++mt)
    #pragma unroll
    for (int nt = 0; nt < 4; ++nt) {
      int m = m0 + wm + mt * 16 + q * 4;
      int n = n0 + wn + nt * 16 + rl;
      #pragma unroll
      for (int reg = 0; reg < 4; ++reg)
        C[(size_t)(m + reg) * 32768 + n] = acc[mt][nt][reg];
    }
}

// ---------------------------------------------------------------------------
// BN column stats over 1024 rows -> scale/shift.
// ---------------------------------------------------------------------------
__global__ __launch_bounds__(256) void bn_stats_kernel(const float* __restrict__ X, int N,
    const float* __restrict__ gamma, const float* __restrict__ beta, int gstride,
    float* __restrict__ scale, float* __restrict__ shift)
{
  const int head = blockIdx.y;
  const float* Xh = X + (size_t)head * 1024 * N;
  const int lane = threadIdx.x & 63;
  const int col  = blockIdx.x * 64 + lane;
  const int rg   = threadIdx.x >> 6;
  float s = 0.f, ss = 0.f;
  const float* p = Xh + (size_t)(rg * 256) * N + col;
  for (int rr = 0; rr < 256; ++rr) { float v = *p; p += N; s += v; ss = fmaf(v, v, ss); }
  __shared__ float Ssum[4][64], Ssq[4][64];
  Ssum[rg][lane] = s; Ssq[rg][lane] = ss;
  __syncthreads();
  if (threadIdx.x < 64) {
    s  = Ssum[0][lane] + Ssum[1][lane] + Ssum[2][lane] + Ssum[3][lane];
    ss = Ssq[0][lane]  + Ssq[1][lane]  + Ssq[2][lane]  + Ssq[3][lane];
    float mean = s * (1.f / 1024.f);
    float var  = ss * (1.f / 1024.f) - mean * mean;
    float sc   = gamma[head * gstride + col] / sqrtf(var + 1e-5f);
    scale[head * N + col] = sc;
    shift[head * N + col] = beta[head * gstride + col] - mean * sc;
  }
}

__global__ void bn_apply_relu_kernel(float* __restrict__ X, int N,
    const float* __restrict__ scale, const float* __restrict__ shift, int total4)
{
  int i = blockIdx.x * 256 + threadIdx.x;
  if (i >= total4) return;
  size_t base = (size_t)i * 4;
  int col  = (int)(base % (size_t)N);
  int head = (int)(base / ((size_t)1024 * N));
  int sb = head * N + col;
  float4 v = *(float4*)&X[base];
  v.x = fmaxf(0.f, fmaf(v.x, scale[sb+0], shift[sb+0]));
  v.y = fmaxf(0.f, fmaf(v.y, scale[sb+1], shift[sb+1]));
  v.z = fmaxf(0.f, fmaf(v.z, scale[sb+2], shift[sb+2]));
  v.w = fmaxf(0.f, fmaf(v.w, scale[sb+3], shift[sb+3]));
  *(float4*)&X[base] = v;
}

__global__ void fuse_combine_kernel(const float* __restrict__ P,
    const float* __restrict__ fwr, const float* __restrict__ fb, float* __restrict__ H)
{
  int i = blockIdx.x * 256 + threadIdx.x;
  if (i >= 131072) return;
  size_t base = (size_t)i * 4;
  int c = (int)(base & 511);
  float4 p0 = ld4(P + base), p1 = ld4(P + 524288 + base), p2 = ld4(P + 1048576 + base);
  float4 w0 = ld4(fwr + c), w1 = ld4(fwr + 512 + c), w2 = ld4(fwr + 1024 + c), b = ld4(fb + c);
  float4 h0, h1, h2, h3;
  h0.x=p0.x+w0.x+b.x; h0.y=p0.y+w0.y+b.y; h0.z=p0.z+w0.z+b.z; h0.w=p0.w+w0.w+b.w;
  h1.x=p1.x+w1.x+b.x; h1.y=p1.y+w1.y+b.y; h1.z=p1.z+w1.z+b.z; h1.w=p1.w+w1.w+b.w;
  h2.x=p2.x+w2.x+b.x; h2.y=p2.y+w2.y+b.y; h2.z=p2.z+w2.z+b.z; h2.w=p2.w+w2.w+b.w;
  h3.x=p0.x+p1.x+p2.x+w0.x+w1.x+w2.x+b.x;
  h3.y=p0.y+p1.y+p2.y+w0.y+w1.y+w2.y+b.y;
  h3.z=p0.z+p1.z+p2.z+w0.z+w1.z+w2.z+b.z;
  h3.w=p0.w+p1.w+p2.w+w0.w+w1.w+w2.w+b.w;
  *(float4*)&H[base]           = h0;
  *(float4*)&H[524288 + base]  = h1;
  *(float4*)&H[1048576 + base] = h2;
  *(float4*)&H[1572864 + base] = h3;
}

__global__ void pack_gb_kernel(const float* __restrict__ sg, const float* __restrict__ sb,
    const float* __restrict__ g, const float* __restrict__ be,
    float* __restrict__ g4, float* __restrict__ b4)
{
  int i = blockIdx.x * 256 + threadIdx.x;
  if (i < 1536)      { g4[i] = sg[i];      b4[i] = sb[i]; }
  else if (i < 2048) { g4[i] = g[i-1536];  b4[i] = be[i-1536]; }
}

__global__ void row_sumsq_kernel(const float* __restrict__ X, float* __restrict__ out, int nrows)
{
  int row  = blockIdx.x * 4 + (threadIdx.x >> 6);
  int lane = threadIdx.x & 63;
  if (row >= nrows) return;
  const float* p = X + (size_t)row * 512 + lane * 8;
  float4 a = ld4(p), b = ld4(p + 4);
  float s = a.x*a.x + a.y*a.y + a.z*a.z + a.w*a.w
          + b.x*b.x + b.y*b.y + b.z*b.z + b.w*b.w;
  for (int off = 32; off; off >>= 1) s += __shfl_down(s, off, 64);
  if (lane == 0) out[row] = s;
}

// ---------------------------------------------------------------------------
// topk_scan1: grid (srows, 4). Block (256) scans a quarter-row (8192 cols)
// with float4 loads, per-thread register top-6, then extracts block-local
// top-16 (approx d2) into cand[grow*64 + cb*16 + sel] = (d2, idx-bits).
// Block-level coverage is exact: global top-16 == top-16 of union of the 4
// block lists. Only per-thread top-6-of-32 is probabilistic (P~1e-13).
// ---------------------------------------------------------------------------
__global__ __launch_bounds__(256) void topk_scan1_kernel(const float* __restrict__ S,
    const float* __restrict__ qn, const float* __restrict__ kn, int rowbase,
    float2* __restrict__ cand)
{
  const int row  = blockIdx.x;
  const int grow = rowbase + row;
  const int cb   = blockIdx.y;            // column quarter 0..3
  const float qnr = qn[grow];
  const float* Srow = S + (size_t)row * 32768 + cb * 8192;
  const float* knb  = kn + cb * 8192;
  const int t = threadIdx.x;
  const float INF = __builtin_inff();

  float vals[6]; int idxs[6];
  #pragma unroll
  for (int j = 0; j < 6; ++j) { vals[j] = INF; idxs[j] = 0x7fffffff; }

  auto ins = [&](float d2, int ci) {
    if (d2 < vals[5] || (d2 == vals[5] && ci < idxs[5])) {
      float cv = d2; int cc = ci;
      #pragma unroll
      for (int j = 0; j < 6; ++j) {
        bool less = (cv < vals[j]) || (cv == vals[j] && cc < idxs[j]);
        float tv = less ? vals[j] : cv; int ti = less ? idxs[j] : cc;
        vals[j] = less ? cv : vals[j]; idxs[j] = less ? cc : idxs[j];
        cv = tv; cc = ti;
      }
    }
  };

  #pragma unroll
  for (int i = 0; i < 8; ++i) {
    int c = (i * 256 + t) * 4;
    float4 s4 = ld4(Srow + c);
    float4 k4 = ld4(knb + c);
    int gcol = cb * 8192 + c;
    ins((qnr + k4.x) - 2.f * s4.x, gcol + 0);
    ins((qnr + k4.y) - 2.f * s4.y, gcol + 1);
    ins((qnr + k4.z) - 2.f * s4.z, gcol + 2);
    ins((qnr + k4.w) - 2.f * s4.w, gcol + 3);
  }

  __shared__ float Wv[4]; __shared__ int Wi[4];
  const int lane = t & 63, wid = t >> 6;
  for (int sel = 0; sel < 16; ++sel) {
    float bv = vals[0]; int bi = idxs[0];
    #pragma unroll
    for (int off = 32; off >= 1; off >>= 1) {
      float ov = __shfl_down(bv, off, 64);
      int   oi = __shfl_down(bi, off, 64);
      if (ov < bv || (ov == bv && oi < bi)) { bv = ov; bi = oi; }
    }
    if (lane == 0) { Wv[wid] = bv; Wi[wid] = bi; }
    __syncthreads();
    float gv = Wv[0]; int gi = Wi[0];
    #pragma unroll
    for (int w2 = 1; w2 < 4; ++w2) {
      float wv2 = Wv[w2]; int wi2 = Wi[w2];
      if (wv2 < gv || (wv2 == gv && wi2 < gi)) { gv = wv2; gi = wi2; }
    }
    if (t == 0) {
      float2 e; e.x = gv; e.y = __int_as_float(gi);
      cand[(size_t)grow * 64 + cb * 16 + sel] = e;
    }
    if (vals[0] == gv && idxs[0] == gi) {   // unique winner pops its head
      #pragma unroll
      for (int j = 0; j < 5; ++j) { vals[j] = vals[j+1]; idxs[j] = idxs[j+1]; }
      vals[5] = INF; idxs[5] = 0x7fffffff;
    }
    __syncthreads();
  }
}

// ---------------------------------------------------------------------------
// topk_rescue2: grid 1024 (one block per row, 256 thr).
// A: wave 0 merges 64 candidates -> approx top-16.  B: exact fp32 d2 for the
// 16 (16 thr each, global reads).  C: exact lexicographic top-10 (wave 0).
// ---------------------------------------------------------------------------
__global__ __launch_bounds__(256) void topk_rescue2_kernel(const float2* __restrict__ cand,
    const float* __restrict__ fusedF, const float* __restrict__ queue,
    const float* __restrict__ qn, const float* __restrict__ kn,
    float* __restrict__ topd2, int* __restrict__ topidx)
{
  const int grow = blockIdx.x;
  const int t = threadIdx.x;
  const float INF = __builtin_inff();
  const float qnr = qn[grow];
  __shared__ int Ci[16]; __shared__ float Cd[16];

  // phase A
  if (t < 64) {
    float2 e = cand[(size_t)grow * 64 + t];
    float v = e.x; int id = __float_as_int(e.y);
    for (int sel = 0; sel < 16; ++sel) {
      float bv = v; int bi = id;
      #pragma unroll
      for (int off = 32; off >= 1; off >>= 1) {
        float ov = __shfl_down(bv, off, 64);
        int   oi = __shfl_down(bi, off, 64);
        if (ov < bv || (ov == bv && oi < bi)) { bv = ov; bi = oi; }
      }
      bv = __shfl(bv, 0, 64); bi = __shfl(bi, 0, 64);
      if (t == 0) Ci[sel] = bi;
      if (id == bi) { v = INF; id = 0x7fffffff; }
    }
  }
  __syncthreads();

  // phase B: exact fp32 d2, 16 threads per candidate
  {
    int c = t >> 4, s = t & 15;
    int qi = Ci[c];
    const float* qp = queue  + (size_t)qi * 512 + s * 32;
    const float* fp = fusedF + (size_t)grow * 512 + s * 32;
    float dot = 0.f;
    #pragma unroll
    for (int j = 0; j < 8; ++j) {
      float4 a = ld4(fp + j*4); float4 b = ld4(qp + j*4);
      dot += a.x*b.x + a.y*b.y + a.z*b.z + a.w*b.w;
    }
    #pragma unroll
    for (int off = 8; off >= 1; off >>= 1) dot += __shfl_down(dot, off, 16);
    if (s == 0) Cd[c] = qnr + kn[qi] - 2.f * dot;
  }
  __syncthreads();

  // phase C: exact lexicographic top-10 of 16 (wave 0)
  if (t < 64) {
    float v = (t < 16) ? Cd[t] : INF;
    int  id = (t < 16) ? Ci[t] : 0x7fffffff;
    for (int sel = 0; sel < TK; ++sel) {
      float bv = v; int bi = id;
      #pragma unroll
      for (int off = 32; off >= 1; off >>= 1) {
        float ov = __shfl_down(bv, off, 64);
        int   oi = __shfl_down(bi, off, 64);
        if (ov < bv || (ov == bv && oi < bi)) { bv = ov; bi = oi; }
      }
      bv = __shfl(bv, 0, 64); bi = __shfl(bi, 0, 64);
      if (t == 0) { topd2[grow*TK + sel] = bv; topidx[grow*TK + sel] = bi; }
      if (id == bi) { v = INF; id = 0x7fffffff; }
    }
  }
}

__global__ void knn_gather_kernel(const float* __restrict__ topd2, const int* __restrict__ topidx,
    const float* __restrict__ queue, float* __restrict__ neigh)
{
  const int row = blockIdx.x;
  const int t = threadIdx.x;   // 64
  __shared__ float ls[TK]; __shared__ float wv[TK]; __shared__ int wid[TK];
  if (t < TK) {
    float d = sqrtf(fmaxf(topd2[row*TK + t], 0.f));
    ls[t]  = -d / 0.07f;
    wid[t] = topidx[row*TK + t];
  }
  __syncthreads();
  if (t < TK) {
    float m = ls[0];
    #pragma unroll
    for (int j = 1; j < TK; ++j) m = fmaxf(m, ls[j]);
    wv[t] = __expf(ls[t] - m);
  }
  __syncthreads();
  float ssum = 0.f;
  #pragma unroll
  for (int j = 0; j < TK; ++j) ssum += wv[j];
  float inv = 1.f / ssum;
  #pragma unroll
  for (int u = 0; u < 8; ++u) {
    int c = u * 64 + t;
    float acc = 0.f;
    #pragma unroll
    for (int k = 0; k < TK; ++k)
      acc = fmaf(wv[k] * inv, queue[(size_t)wid[k] * 512 + c], acc);
    neigh[(size_t)row * 512 + c] = acc;
  }
}

__global__ void gemm_n18_kernel(const float* __restrict__ Z, const float* __restrict__ W2,
    const float* __restrict__ b2, float* __restrict__ out, int Mrows)
{
  int o = blockIdx.x * 256 + threadIdx.x;
  if (o >= Mrows * 18) return;
  int r = o / 18, c = o - r * 18;
  const float* zp = Z + (size_t)r * 512;
  float acc = b2[c];
  #pragma unroll 8
  for (int k = 0; k < 512; ++k) acc = fmaf(zp[k], W2[k*18 + c], acc);
  out[o] = acc;
}

// ---------------------------------------------------------------------------
extern "C" void kernel_launch(void* const* d_in, const int* in_sizes, int n_in,
                              void* d_out, int out_size, void* d_ws, size_t ws_size,
                              hipStream_t stream)
{
  #define IN(i) ((const float*)d_in[i])
  const float* img_feat = IN(0);
  const float* option   = IN(1);
  const float* semantic = IN(2);
  const float* queue    = IN(3);
  const float* vae_w1 = IN(4);  const float* vae_b1 = IN(5);
  const float* vae_g1 = IN(6);  const float* vae_be1 = IN(7);
  const float* vae_w2 = IN(8);  const float* vae_b2 = IN(9);
  const float* opt_w1 = IN(10); const float* opt_b1 = IN(11);
  const float* opt_g1 = IN(12); const float* opt_be1 = IN(13);
  const float* opt_w2 = IN(14); const float* opt_b2 = IN(15);
  const float* opt_g2 = IN(16); const float* opt_be2 = IN(17);
  const float* sem_w1 = IN(18); const float* sem_b1 = IN(19);
  const float* sem_g1 = IN(20); const float* sem_be1 = IN(21);
  const float* sem_w2 = IN(22); const float* sem_b2 = IN(23);
  const float* sem_g2 = IN(24); const float* sem_be2 = IN(25);
  const float* fus_w = IN(26);  const float* fus_b = IN(27);
  const float* fus_g = IN(28);  const float* fus_be = IN(29);
  const float* fus_sg = IN(30); const float* fus_sb = IN(31);
  const float* cls_w1 = IN(32); const float* cls_b1 = IN(33);
  const float* cls_g = IN(34);  const float* cls_be = IN(35);
  const float* cls_w2 = IN(36); const float* cls_b2 = IN(37);

  float* ws = (float*)d_ws;
  size_t off = 0;
  auto alloc = [&](size_t n) { float* p = ws + off; off += (n + 255) & ~(size_t)255; return p; };

  const int srows = (ws_size >= (size_t)74 * 1024 * 1024) ? 256 : 128;

  float* S    = alloc((size_t)srows * 32768);
  float* H    = alloc(4 * 1024 * 512);
  float* Z4   = alloc(4 * 1024 * 512);
  float* zstart = ws + off;          // ---- region zeroed for split-K atomics ----
  float* t1   = alloc(1024 * 512);
  float* img  = alloc(1024 * 512);
  float* o1   = alloc(1024 * 192);
  float* optb = alloc(1024 * 512);
  float* s1   = alloc(1024 * 192);
  float* semb = alloc(1024 * 512);
  float* P    = alloc(3 * 1024 * 512);
  float* Z1   = alloc(1024 * 512);
  size_t zbytes = (size_t)((ws + off) - zstart) * 4;   // ---- end zero region ----
  float* neigh = alloc(1024 * 512);
  float* qn   = alloc(1024);
  float* kn   = alloc(32768);
  float2* cand = (float2*)alloc(1024 * 64 * 2);
  float* scv  = alloc(512);  float* shv  = alloc(512);
  float* sco1 = alloc(192);  float* sho1 = alloc(192);
  float* sco2 = alloc(512);  float* sho2 = alloc(512);
  float* scs1 = alloc(192);  float* shs1 = alloc(192);
  float* scs2 = alloc(512);  float* shs2 = alloc(512);
  float* scf  = alloc(4*512); float* shf = alloc(4*512);
  float* scc4 = alloc(4*512); float* shc4 = alloc(4*512);
  float* scc1 = alloc(512);  float* shc1 = alloc(512);
  float* g4   = alloc(4*512); float* b4  = alloc(4*512);
  float* topd2 = alloc(1024 * TK);
  int*   topidx = (int*)alloc(1024 * TK);

  hipMemsetAsync(zstart, 0, zbytes, stream);

  dim3 blk(256);
  // --- VAE branch
  gemm64_kernel<<<dim3(8,16,4), blk, 0, stream>>>(img_feat, vae_w1, vae_b1, t1, 1024, 512, 2048);
  bn_stats_kernel<<<dim3(8,1), blk, 0, stream>>>(t1, 512, vae_g1, vae_be1, 0, scv, shv);
  bn_apply_relu_kernel<<<dim3(512), blk, 0, stream>>>(t1, 512, scv, shv, 131072);
  gemm64_kernel<<<dim3(8,16,4), blk, 0, stream>>>(t1, vae_w2, vae_b2, img, 1024, 512, 512);
  // --- option encoder
  gemm64_kernel<<<dim3(3,16,8), blk, 0, stream>>>(option, opt_w1, opt_b1, o1, 1024, 192, 768);
  bn_stats_kernel<<<dim3(3,1), blk, 0, stream>>>(o1, 192, opt_g1, opt_be1, 0, sco1, sho1);
  bn_apply_relu_kernel<<<dim3(192), blk, 0, stream>>>(o1, 192, sco1, sho1, 49152);
  gemm64_kernel<<<dim3(8,16,2), blk, 0, stream>>>(o1, opt_w2, opt_b2, optb, 1024, 512, 192);
  bn_stats_kernel<<<dim3(8,1), blk, 0, stream>>>(optb, 512, opt_g2, opt_be2, 0, sco2, sho2);
  bn_apply_relu_kernel<<<dim3(512), blk, 0, stream>>>(optb, 512, sco2, sho2, 131072);
  // --- semantic encoder
  gemm64_kernel<<<dim3(3,16,8), blk, 0, stream>>>(semantic, sem_w1, sem_b1, s1, 1024, 192, 768);
  bn_stats_kernel<<<dim3(3,1), blk, 0, stream>>>(s1, 192, sem_g1, sem_be1, 0, scs1, shs1);
  bn_apply_relu_kernel<<<dim3(192), blk, 0, stream>>>(s1, 192, scs1, shs1, 49152);
  gemm64_kernel<<<dim3(8,16,2), blk, 0, stream>>>(s1, sem_w2, sem_b2, semb, 1024, 512, 192);
  bn_stats_kernel<<<dim3(8,1), blk, 0, stream>>>(semb, 512, sem_g2, sem_be2, 0, scs2, shs2);
  bn_apply_relu_kernel<<<dim3(512), blk, 0, stream>>>(semb, 512, scs2, shs2, 131072);
  // --- fusion
  gemm64_kernel<<<dim3(8,16,4), blk, 0, stream>>>(img,  fus_w,          nullptr, P,           1024, 512, 512);
  gemm64_kernel<<<dim3(8,16,4), blk, 0, stream>>>(optb, fus_w + 262144, nullptr, P + 524288,  1024, 512, 512);
  gemm64_kernel<<<dim3(8,16,4), blk, 0, stream>>>(semb, fus_w + 524288, nullptr, P + 1048576, 1024, 512, 512);
  fuse_combine_kernel<<<dim3(512), blk, 0, stream>>>(P, fus_w + 1536*512, fus_b, H);
  pack_gb_kernel<<<dim3(8), blk, 0, stream>>>(fus_sg, fus_sb, fus_g, fus_be, g4, b4);
  bn_stats_kernel<<<dim3(8,4), blk, 0, stream>>>(H, 512, g4, b4, 512, scf, shf);
  bn_apply_relu_kernel<<<dim3(2048), blk, 0, stream>>>(H, 512, scf, shf, 524288);
  // --- classifier on heads 0..3
  gemm64_kernel<<<dim3(8,64,1), blk, 0, stream>>>(H, cls_w1, cls_b1, Z4, 4096, 512, 512);
  bn_stats_kernel<<<dim3(8,4), blk, 0, stream>>>(Z4, 512, cls_g, cls_be, 0, scc4, shc4);
  bn_apply_relu_kernel<<<dim3(2048), blk, 0, stream>>>(Z4, 512, scc4, shc4, 524288);
  gemm_n18_kernel<<<dim3((4096*18 + 255)/256), blk, 0, stream>>>(Z4, cls_w2, cls_b2, (float*)d_out, 4096);
  // --- kNN retrieval: bf16-MFMA approx scores + 2-stage exact rescue
  const float* fused = H + (size_t)3 * 1024 * 512;
  row_sumsq_kernel<<<dim3(256), blk, 0, stream>>>(fused, qn, 1024);
  row_sumsq_kernel<<<dim3(8192), blk, 0, stream>>>(queue, kn, 32768);
  for (int sbase = 0; sbase < 1024; sbase += srows) {
    score_mfma_kernel<<<dim3(256, srows/128), blk, 0, stream>>>(fused + (size_t)sbase*512, queue, S);
    topk_scan1_kernel<<<dim3(srows, 4), blk, 0, stream>>>(S, qn, kn, sbase, cand);
  }
  topk_rescue2_kernel<<<dim3(1024), blk, 0, stream>>>(cand, fused, queue, qn, kn, topd2, topidx);
  knn_gather_kernel<<<dim3(1024), dim3(64), 0, stream>>>(topd2, topidx, queue, neigh);
  // --- classifier on neigh (head 4)
  gemm64_kernel<<<dim3(8,16,4), blk, 0, stream>>>(neigh, cls_w1, cls_b1, Z1, 1024, 512, 512);
  bn_stats_kernel<<<dim3(8,1), blk, 0, stream>>>(Z1, 512, cls_g, cls_be, 0, scc1, shc1);
  bn_apply_relu_kernel<<<dim3(512), blk, 0, stream>>>(Z1, 512, scc1, shc1, 131072);
  gemm_n18_kernel<<<dim3((1024*18 + 255)/256), blk, 0, stream>>>(Z1, cls_w2, cls_b2, (float*)d_out + 4*1024*18, 1024);
  #undef IN
}